// Round 2
// baseline (4969.563 us; speedup 1.0000x reference)
//
#include <hip/hip_runtime.h>

// GAT: h=x@Ew+eb; 2x GATConv(4 heads x 32) + relu; GATConv(1 head x 64).
// Segment softmax over dst via atomic passes (ordered-uint atomicMax, atomicAdd).

__device__ __forceinline__ unsigned fkey(float f) {
  int i = __float_as_int(f);
  return (i >= 0) ? ((unsigned)i | 0x80000000u) : ~(unsigned)i;
}
__device__ __forceinline__ float fdec(unsigned u) {
  int i = (u & 0x80000000u) ? (int)(u & 0x7fffffffu) : ~(int)u;
  return __int_as_float(i);
}
__device__ __forceinline__ float lrelu(float v) { return v >= 0.f ? v : 0.2f * v; }

// ---------------- GEMM: Y[n,OUTC] = X[n,128] @ W[128,OUTC] (+bias) ----------------
template <int OUTC, bool BIAS>
__global__ __launch_bounds__(256) void gemm_k(const float* __restrict__ X,
                                              const float* __restrict__ W,
                                              const float* __restrict__ B,
                                              float* __restrict__ Y, int n) {
  __shared__ float sW[128 * OUTC];
  __shared__ float sX[32 * 128];
  for (int i = threadIdx.x * 4; i < 128 * OUTC; i += 256 * 4)
    *(float4*)&sW[i] = *(const float4*)&W[i];
  int row0 = blockIdx.x * 32;
  for (int i = threadIdx.x * 4; i < 32 * 128; i += 256 * 4) {
    int r = i >> 7, c = i & 127;
    int gr = row0 + r;
    float4 v = make_float4(0.f, 0.f, 0.f, 0.f);
    if (gr < n) v = *(const float4*)&X[(size_t)gr * 128 + c];
    *(float4*)&sX[i] = v;
  }
  __syncthreads();
  const int tx = threadIdx.x & 31;   // col group
  const int ty = threadIdx.x >> 5;   // row group 0..7
  constexpr int CPT = OUTC / 32;     // 4 (OUTC=128) or 2 (OUTC=64)
  const int c0 = tx * CPT;
  const int r0 = ty * 4;
  float acc[4][CPT];
#pragma unroll
  for (int r = 0; r < 4; r++)
#pragma unroll
    for (int c = 0; c < CPT; c++) acc[r][c] = 0.f;

  for (int k = 0; k < 128; k += 4) {
    float4 xv0 = *(float4*)&sX[(r0 + 0) * 128 + k];
    float4 xv1 = *(float4*)&sX[(r0 + 1) * 128 + k];
    float4 xv2 = *(float4*)&sX[(r0 + 2) * 128 + k];
    float4 xv3 = *(float4*)&sX[(r0 + 3) * 128 + k];
#pragma unroll
    for (int kk = 0; kk < 4; kk++) {
      float w[CPT];
#pragma unroll
      for (int c = 0; c < CPT; c++) w[c] = sW[(k + kk) * OUTC + c0 + c];
      float x0 = (&xv0.x)[kk], x1 = (&xv1.x)[kk], x2 = (&xv2.x)[kk], x3 = (&xv3.x)[kk];
#pragma unroll
      for (int c = 0; c < CPT; c++) {
        acc[0][c] = fmaf(x0, w[c], acc[0][c]);
        acc[1][c] = fmaf(x1, w[c], acc[1][c]);
        acc[2][c] = fmaf(x2, w[c], acc[2][c]);
        acc[3][c] = fmaf(x3, w[c], acc[3][c]);
      }
    }
  }
#pragma unroll
  for (int r = 0; r < 4; r++) {
    int gr = row0 + r0 + r;
    if (gr < n) {
#pragma unroll
      for (int c = 0; c < CPT; c++) {
        float v = acc[r][c];
        if (BIAS) v += B[c0 + c];
        Y[(size_t)gr * OUTC + c0 + c] = v;
      }
    }
  }
}

// ---------------- per-node attention coefficients ----------------
template <int NH, int CH>
__global__ __launch_bounds__(256) void attn_coef_k(const float* __restrict__ H,
                                                   const float* __restrict__ AS,
                                                   const float* __restrict__ AD,
                                                   float* __restrict__ es,
                                                   float* __restrict__ ed, int n) {
  int nidx = blockIdx.x * 256 + threadIdx.x;
  if (nidx >= n) return;
  const float* h = H + (size_t)nidx * (NH * CH);
#pragma unroll
  for (int hh = 0; hh < NH; hh++) {
    float s = 0.f, d = 0.f;
#pragma unroll
    for (int c = 0; c < CH; c += 4) {
      float4 hv = *(const float4*)&h[hh * CH + c];
      float4 av = *(const float4*)&AS[hh * CH + c];
      float4 dv = *(const float4*)&AD[hh * CH + c];
      s += hv.x * av.x + hv.y * av.y + hv.z * av.z + hv.w * av.w;
      d += hv.x * dv.x + hv.y * dv.y + hv.z * dv.z + hv.w * dv.w;
    }
    es[(size_t)nidx * NH + hh] = s;
    ed[(size_t)nidx * NH + hh] = d;
  }
}

// ---------------- edge pass A: segment max (ordered-uint atomicMax) ----------------
template <int NH>
__global__ __launch_bounds__(256) void edge_max_k(const float* __restrict__ es,
                                                  const float* __restrict__ ed,
                                                  const int* __restrict__ src,
                                                  const int* __restrict__ dst,
                                                  unsigned* __restrict__ mu, int ET) {
  int e = blockIdx.x * 256 + threadIdx.x;
  if (e >= ET) return;
  int s = src[e], d = dst[e];
#pragma unroll
  for (int h = 0; h < NH; h++) {
    float v = lrelu(es[(size_t)s * NH + h] + ed[(size_t)d * NH + h]);
    atomicMax(&mu[(size_t)d * NH + h], fkey(v));
  }
}

// ---------------- edge pass B: denominators ----------------
template <int NH>
__global__ __launch_bounds__(256) void edge_den_k(const float* __restrict__ es,
                                                  const float* __restrict__ ed,
                                                  const int* __restrict__ src,
                                                  const int* __restrict__ dst,
                                                  const unsigned* __restrict__ mu,
                                                  float* __restrict__ den, int ET) {
  int e = blockIdx.x * 256 + threadIdx.x;
  if (e >= ET) return;
  int s = src[e], d = dst[e];
#pragma unroll
  for (int h = 0; h < NH; h++) {
    float v = lrelu(es[(size_t)s * NH + h] + ed[(size_t)d * NH + h]);
    atomicAdd(&den[(size_t)d * NH + h], expf(v - fdec(mu[(size_t)d * NH + h])));
  }
}

// ---------------- edge pass C: aggregate (wave per edge) ----------------
// 4 heads x 32 ch = 128 channels, 2 per lane
__global__ __launch_bounds__(256) void edge_aggr128_k(const float* __restrict__ H,
                                                      const float* __restrict__ es,
                                                      const float* __restrict__ ed,
                                                      const unsigned* __restrict__ mu,
                                                      const float* __restrict__ den,
                                                      const int* __restrict__ src,
                                                      const int* __restrict__ dst,
                                                      float* __restrict__ out, int ET) {
  int e = blockIdx.x * 4 + (threadIdx.x >> 6);
  if (e >= ET) return;
  int lane = threadIdx.x & 63;
  int s = src[e], d = dst[e];
  int head = lane >> 4;  // (2*lane)/32
  float v = lrelu(es[(size_t)s * 4 + head] + ed[(size_t)d * 4 + head]);
  float alpha = expf(v - fdec(mu[(size_t)d * 4 + head])) / den[(size_t)d * 4 + head];
  float2 hv = *(const float2*)&H[(size_t)s * 128 + lane * 2];
  atomicAdd(&out[(size_t)d * 128 + lane * 2], hv.x * alpha);
  atomicAdd(&out[(size_t)d * 128 + lane * 2 + 1], hv.y * alpha);
}

// 1 head x 64 ch, 1 per lane
__global__ __launch_bounds__(256) void edge_aggr64_k(const float* __restrict__ H,
                                                     const float* __restrict__ es,
                                                     const float* __restrict__ ed,
                                                     const unsigned* __restrict__ mu,
                                                     const float* __restrict__ den,
                                                     const int* __restrict__ src,
                                                     const int* __restrict__ dst,
                                                     float* __restrict__ out, int ET) {
  int e = blockIdx.x * 4 + (threadIdx.x >> 6);
  if (e >= ET) return;
  int lane = threadIdx.x & 63;
  int s = src[e], d = dst[e];
  float v = lrelu(es[s] + ed[d]);
  float alpha = expf(v - fdec(mu[d])) / den[d];
  atomicAdd(&out[(size_t)d * 64 + lane], H[(size_t)s * 64 + lane] * alpha);
}

// ---------------- bias (+relu) epilogue ----------------
template <int OUTC, bool RELU>
__global__ __launch_bounds__(256) void bias_act_k(float* __restrict__ Y,
                                                  const float* __restrict__ B,
                                                  size_t total) {
  size_t i = (size_t)blockIdx.x * 256 + threadIdx.x;
  if (i >= total) return;
  int c = (int)(i & (OUTC - 1));
  float v = Y[i] + B[c];
  Y[i] = RELU ? fmaxf(v, 0.f) : v;
}

extern "C" void kernel_launch(void* const* d_in, const int* in_sizes, int n_in,
                              void* d_out, int out_size, void* d_ws, size_t ws_size,
                              hipStream_t stream) {
  const float* x = (const float*)d_in[0];
  const float* encw = (const float*)d_in[2];
  const float* encb = (const float*)d_in[3];
  const float* W1 = (const float*)d_in[4];
  const float* as1 = (const float*)d_in[5];
  const float* ad1 = (const float*)d_in[6];
  const float* b1 = (const float*)d_in[7];
  const float* W2 = (const float*)d_in[8];
  const float* as2 = (const float*)d_in[9];
  const float* ad2 = (const float*)d_in[10];
  const float* b2 = (const float*)d_in[11];
  const float* W3 = (const float*)d_in[12];
  const float* as3 = (const float*)d_in[13];
  const float* ad3 = (const float*)d_in[14];
  const float* b3 = (const float*)d_in[15];
  const int* ei = (const int*)d_in[16];

  const int N_ = in_sizes[0] / 128;
  const int ET = in_sizes[16] / 2;
  const int* srcp = ei;
  const int* dstp = ei + ET;
  float* out = (float*)d_out;

  // workspace carve-up (~109 MB)
  size_t NB = (size_t)N_ * 128 * sizeof(float);
  float* bufA = (float*)d_ws;
  float* bufB = (float*)((char*)d_ws + NB);
  char* p = (char*)d_ws + 2 * NB;
  float* es = (float*)p;        p += (size_t)N_ * 4 * sizeof(float);
  float* ed = (float*)p;        p += (size_t)N_ * 4 * sizeof(float);
  unsigned* mu = (unsigned*)p;  p += (size_t)N_ * 4 * sizeof(unsigned);
  float* den = (float*)p;

  dim3 b256(256);
  int gGemm = (N_ + 31) / 32;
  int gNode = (N_ + 255) / 256;
  int gEdge = (ET + 255) / 256;
  int gAggr = (ET + 3) / 4;
  int gEl128 = (int)(((size_t)N_ * 128 + 255) / 256);
  int gEl64 = (int)(((size_t)N_ * 64 + 255) / 256);

  // encode: bufA = x @ enc_w + enc_b
  gemm_k<128, true><<<gGemm, b256, 0, stream>>>(x, encw, encb, bufA, N_);

  // ---- layer 1 (4 heads x 32) ----
  gemm_k<128, false><<<gGemm, b256, 0, stream>>>(bufA, W1, nullptr, bufB, N_);
  attn_coef_k<4, 32><<<gNode, b256, 0, stream>>>(bufB, as1, ad1, es, ed, N_);
  hipMemsetAsync(mu, 0, (size_t)N_ * 4 * 4, stream);
  hipMemsetAsync(den, 0, (size_t)N_ * 4 * 4, stream);
  hipMemsetAsync(bufA, 0, NB, stream);  // bufA consumed by gemm above; now becomes accum
  edge_max_k<4><<<gEdge, b256, 0, stream>>>(es, ed, srcp, dstp, mu, ET);
  edge_den_k<4><<<gEdge, b256, 0, stream>>>(es, ed, srcp, dstp, mu, den, ET);
  edge_aggr128_k<<<gAggr, b256, 0, stream>>>(bufB, es, ed, mu, den, srcp, dstp, bufA, ET);
  bias_act_k<128, true><<<gEl128, b256, 0, stream>>>(bufA, b1, (size_t)N_ * 128);

  // ---- layer 2 (4 heads x 32) ----
  gemm_k<128, false><<<gGemm, b256, 0, stream>>>(bufA, W2, nullptr, bufB, N_);
  attn_coef_k<4, 32><<<gNode, b256, 0, stream>>>(bufB, as2, ad2, es, ed, N_);
  hipMemsetAsync(mu, 0, (size_t)N_ * 4 * 4, stream);
  hipMemsetAsync(den, 0, (size_t)N_ * 4 * 4, stream);
  hipMemsetAsync(bufA, 0, NB, stream);
  edge_max_k<4><<<gEdge, b256, 0, stream>>>(es, ed, srcp, dstp, mu, ET);
  edge_den_k<4><<<gEdge, b256, 0, stream>>>(es, ed, srcp, dstp, mu, den, ET);
  edge_aggr128_k<<<gAggr, b256, 0, stream>>>(bufB, es, ed, mu, den, srcp, dstp, bufA, ET);
  bias_act_k<128, true><<<gEl128, b256, 0, stream>>>(bufA, b2, (size_t)N_ * 128);

  // ---- layer 3 (1 head x 64) -> d_out ----
  gemm_k<64, false><<<gGemm, b256, 0, stream>>>(bufA, W3, nullptr, bufB, N_);
  attn_coef_k<1, 64><<<gNode, b256, 0, stream>>>(bufB, as3, ad3, es, ed, N_);
  hipMemsetAsync(mu, 0, (size_t)N_ * 4, stream);
  hipMemsetAsync(den, 0, (size_t)N_ * 4, stream);
  hipMemsetAsync(out, 0, (size_t)N_ * 64 * 4, stream);
  edge_max_k<1><<<gEdge, b256, 0, stream>>>(es, ed, srcp, dstp, mu, ET);
  edge_den_k<1><<<gEdge, b256, 0, stream>>>(es, ed, srcp, dstp, mu, den, ET);
  edge_aggr64_k<<<gAggr, b256, 0, stream>>>(bufB, es, ed, mu, den, srcp, dstp, out, ET);
  bias_act_k<64, false><<<gEl64, b256, 0, stream>>>(out, b3, (size_t)N_ * 64);
}

// Round 3
// 1096.285 us; speedup vs baseline: 4.5331x; 4.5331x over previous
//
#include <hip/hip_runtime.h>

// GAT via device-built CSR: h=x@Ew+eb; 2x GATConv(4x32)+relu; GATConv(1x64).
// CSR built once per launch (same edge_index for all layers); per-layer fused
// segment-softmax + aggregation kernel, one wave per dst node.

__device__ __forceinline__ float lrelu(float v) { return v >= 0.f ? v : 0.2f * v; }

// ---------------- GEMM: Y[n,OUTC] = X[n,128] @ W[128,OUTC] (+bias) ----------------
template <int OUTC, bool BIAS>
__global__ __launch_bounds__(256) void gemm_k(const float* __restrict__ X,
                                              const float* __restrict__ W,
                                              const float* __restrict__ B,
                                              float* __restrict__ Y, int n) {
  __shared__ float sW[128 * OUTC];
  __shared__ float sX[32 * 128];
  for (int i = threadIdx.x * 4; i < 128 * OUTC; i += 256 * 4)
    *(float4*)&sW[i] = *(const float4*)&W[i];
  int row0 = blockIdx.x * 32;
  for (int i = threadIdx.x * 4; i < 32 * 128; i += 256 * 4) {
    int r = i >> 7, c = i & 127;
    int gr = row0 + r;
    float4 v = make_float4(0.f, 0.f, 0.f, 0.f);
    if (gr < n) v = *(const float4*)&X[(size_t)gr * 128 + c];
    *(float4*)&sX[i] = v;
  }
  __syncthreads();
  const int tx = threadIdx.x & 31;
  const int ty = threadIdx.x >> 5;
  constexpr int CPT = OUTC / 32;
  const int c0 = tx * CPT;
  const int r0 = ty * 4;
  float acc[4][CPT];
#pragma unroll
  for (int r = 0; r < 4; r++)
#pragma unroll
    for (int c = 0; c < CPT; c++) acc[r][c] = 0.f;

  for (int k = 0; k < 128; k += 4) {
    float4 xv0 = *(float4*)&sX[(r0 + 0) * 128 + k];
    float4 xv1 = *(float4*)&sX[(r0 + 1) * 128 + k];
    float4 xv2 = *(float4*)&sX[(r0 + 2) * 128 + k];
    float4 xv3 = *(float4*)&sX[(r0 + 3) * 128 + k];
#pragma unroll
    for (int kk = 0; kk < 4; kk++) {
      float w[CPT];
#pragma unroll
      for (int c = 0; c < CPT; c++) w[c] = sW[(k + kk) * OUTC + c0 + c];
      float x0 = (&xv0.x)[kk], x1 = (&xv1.x)[kk], x2 = (&xv2.x)[kk], x3 = (&xv3.x)[kk];
#pragma unroll
      for (int c = 0; c < CPT; c++) {
        acc[0][c] = fmaf(x0, w[c], acc[0][c]);
        acc[1][c] = fmaf(x1, w[c], acc[1][c]);
        acc[2][c] = fmaf(x2, w[c], acc[2][c]);
        acc[3][c] = fmaf(x3, w[c], acc[3][c]);
      }
    }
  }
#pragma unroll
  for (int r = 0; r < 4; r++) {
    int gr = row0 + r0 + r;
    if (gr < n) {
#pragma unroll
      for (int c = 0; c < CPT; c++) {
        float v = acc[r][c];
        if (BIAS) v += B[c0 + c];
        Y[(size_t)gr * OUTC + c0 + c] = v;
      }
    }
  }
}

// ---------------- per-node attention coefficients ----------------
template <int NH, int CH>
__global__ __launch_bounds__(256) void attn_coef_k(const float* __restrict__ H,
                                                   const float* __restrict__ AS,
                                                   const float* __restrict__ AD,
                                                   float* __restrict__ es,
                                                   float* __restrict__ ed, int n) {
  int nidx = blockIdx.x * 256 + threadIdx.x;
  if (nidx >= n) return;
  const float* h = H + (size_t)nidx * (NH * CH);
#pragma unroll
  for (int hh = 0; hh < NH; hh++) {
    float s = 0.f, d = 0.f;
#pragma unroll
    for (int c = 0; c < CH; c += 4) {
      float4 hv = *(const float4*)&h[hh * CH + c];
      float4 av = *(const float4*)&AS[hh * CH + c];
      float4 dv = *(const float4*)&AD[hh * CH + c];
      s += hv.x * av.x + hv.y * av.y + hv.z * av.z + hv.w * av.w;
      d += hv.x * dv.x + hv.y * dv.y + hv.z * dv.z + hv.w * dv.w;
    }
    es[(size_t)nidx * NH + hh] = s;
    ed[(size_t)nidx * NH + hh] = d;
  }
}

// ---------------- CSR build ----------------
__global__ __launch_bounds__(256) void count_k(const int* __restrict__ dst,
                                               int* __restrict__ cnt, int ET) {
  int e = blockIdx.x * 256 + threadIdx.x;
  if (e < ET) atomicAdd(&cnt[dst[e]], 1);
}

// per-block exclusive scan of cnt -> row_ptr (block-local), block total -> bsum
__global__ __launch_bounds__(256) void block_scan_k(const int* __restrict__ cnt,
                                                    int* __restrict__ row_ptr,
                                                    int* __restrict__ bsum, int n) {
  __shared__ int s[256];
  int t = threadIdx.x;
  int idx = blockIdx.x * 256 + t;
  int val = (idx < n) ? cnt[idx] : 0;
  s[t] = val;
  __syncthreads();
  for (int off = 1; off < 256; off <<= 1) {
    int x = (t >= off) ? s[t - off] : 0;
    __syncthreads();
    s[t] += x;
    __syncthreads();
  }
  if (idx < n) row_ptr[idx] = s[t] - val;  // exclusive
  if (t == 255) bsum[blockIdx.x] = s[255];
}

__global__ void bsum_scan_k(int* __restrict__ bsum, int nb) {
  if (blockIdx.x == 0 && threadIdx.x == 0) {
    int run = 0;
    for (int i = 0; i < nb; i++) {
      int v = bsum[i];
      bsum[i] = run;
      run += v;
    }
  }
}

__global__ __launch_bounds__(256) void add_off_k(int* __restrict__ row_ptr,
                                                 const int* __restrict__ bsum,
                                                 int n, int ET) {
  int idx = blockIdx.x * 256 + threadIdx.x;
  if (idx < n) row_ptr[idx] += bsum[idx >> 8];
  if (idx == 0) row_ptr[n] = ET;
}

__global__ __launch_bounds__(256) void fill_k(const int* __restrict__ src,
                                              const int* __restrict__ dst,
                                              int* __restrict__ cursor,
                                              int* __restrict__ csr_src, int ET) {
  int e = blockIdx.x * 256 + threadIdx.x;
  if (e >= ET) return;
  int pos = atomicAdd(&cursor[dst[e]], 1);
  csr_src[pos] = src[e];
}

// ---------------- fused segment softmax + aggregation (one wave / dst) --------
// NH*CH channels total (128 or 64). CPL = channels per lane.
template <int NH, int CH, bool RELU>
__global__ __launch_bounds__(256) void aggr_csr_k(const float* __restrict__ H,
                                                  const float* __restrict__ es,
                                                  const float* __restrict__ ed,
                                                  const int* __restrict__ row_ptr,
                                                  const int* __restrict__ csr_src,
                                                  const float* __restrict__ bias,
                                                  float* __restrict__ out, int n) {
  constexpr int NC = NH * CH;
  constexpr int CPL = NC / 64;
  constexpr int CAP = 128;  // LDS-cached src indices per wave
  __shared__ int sE[4][CAP];

  int w = threadIdx.x >> 6;  // wave in block
  int d = blockIdx.x * 4 + w;
  if (d >= n) return;
  int lane = threadIdx.x & 63;
  int beg = row_ptr[d], end = row_ptr[d + 1];
  int deg = end - beg;

  // stage src list in LDS (reused by all 3 phases)
  for (int i = lane; i < deg && i < CAP; i += 64) sE[w][i] = csr_src[beg + i];
  // wave-local producer/consumer only -> no barrier needed beyond wave sync
  __builtin_amdgcn_wave_barrier();

  // dst coefficients (wave-uniform)
  float edv[NH];
#pragma unroll
  for (int h = 0; h < NH; h++) edv[h] = ed[(size_t)d * NH + h];

  // ---- phase 1: per-head max over edges ----
  float mx[NH];
#pragma unroll
  for (int h = 0; h < NH; h++) mx[h] = -INFINITY;
  for (int i = lane; i < deg; i += 64) {
    int s = (i < CAP) ? sE[w][i] : csr_src[beg + i];
    if (NH == 4) {
      float4 e4 = *(const float4*)&es[(size_t)s * 4];
      mx[0] = fmaxf(mx[0], lrelu(e4.x + edv[0]));
      mx[1] = fmaxf(mx[1], lrelu(e4.y + edv[1]));
      mx[2] = fmaxf(mx[2], lrelu(e4.z + edv[2]));
      mx[3] = fmaxf(mx[3], lrelu(e4.w + edv[3]));
    } else {
      mx[0] = fmaxf(mx[0], lrelu(es[s] + edv[0]));
    }
  }
#pragma unroll
  for (int off = 32; off; off >>= 1)
#pragma unroll
    for (int h = 0; h < NH; h++) mx[h] = fmaxf(mx[h], __shfl_xor(mx[h], off, 64));

  // ---- phase 2: denominators ----
  float den[NH];
#pragma unroll
  for (int h = 0; h < NH; h++) den[h] = 0.f;
  for (int i = lane; i < deg; i += 64) {
    int s = (i < CAP) ? sE[w][i] : csr_src[beg + i];
    if (NH == 4) {
      float4 e4 = *(const float4*)&es[(size_t)s * 4];
      den[0] += expf(lrelu(e4.x + edv[0]) - mx[0]);
      den[1] += expf(lrelu(e4.y + edv[1]) - mx[1]);
      den[2] += expf(lrelu(e4.z + edv[2]) - mx[2]);
      den[3] += expf(lrelu(e4.w + edv[3]) - mx[3]);
    } else {
      den[0] += expf(lrelu(es[s] + edv[0]) - mx[0]);
    }
  }
#pragma unroll
  for (int off = 32; off; off >>= 1)
#pragma unroll
    for (int h = 0; h < NH; h++) den[h] += __shfl_xor(den[h], off, 64);

  // ---- phase 3: channel-parallel weighted accumulate ----
  const int ch0 = lane * CPL;
  const int head = ch0 / CH;
  const float m_h = mx[(NH == 4) ? head : 0];
  const float dn_h = den[(NH == 4) ? head : 0];
  const float ed_h = edv[(NH == 4) ? head : 0];
  float acc[CPL];
#pragma unroll
  for (int c = 0; c < CPL; c++) acc[c] = 0.f;

  for (int i = 0; i < deg; i++) {
    int s = (i < CAP) ? sE[w][i] : csr_src[beg + i];
    float alpha = expf(lrelu(es[(size_t)s * NH + head] + ed_h) - m_h) / dn_h;
    if (CPL == 2) {
      float2 hv = *(const float2*)&H[(size_t)s * NC + ch0];
      acc[0] = fmaf(hv.x, alpha, acc[0]);
      acc[1] = fmaf(hv.y, alpha, acc[1]);
    } else {
      acc[0] = fmaf(H[(size_t)s * NC + ch0], alpha, acc[0]);
    }
  }

#pragma unroll
  for (int c = 0; c < CPL; c++) {
    float v = acc[c] + bias[ch0 + c];
    out[(size_t)d * NC + ch0 + c] = RELU ? fmaxf(v, 0.f) : v;
  }
}

extern "C" void kernel_launch(void* const* d_in, const int* in_sizes, int n_in,
                              void* d_out, int out_size, void* d_ws, size_t ws_size,
                              hipStream_t stream) {
  const float* x = (const float*)d_in[0];
  const float* encw = (const float*)d_in[2];
  const float* encb = (const float*)d_in[3];
  const float* W1 = (const float*)d_in[4];
  const float* as1 = (const float*)d_in[5];
  const float* ad1 = (const float*)d_in[6];
  const float* b1 = (const float*)d_in[7];
  const float* W2 = (const float*)d_in[8];
  const float* as2 = (const float*)d_in[9];
  const float* ad2 = (const float*)d_in[10];
  const float* b2 = (const float*)d_in[11];
  const float* W3 = (const float*)d_in[12];
  const float* as3 = (const float*)d_in[13];
  const float* ad3 = (const float*)d_in[14];
  const float* b3 = (const float*)d_in[15];
  const int* ei = (const int*)d_in[16];

  const int N_ = in_sizes[0] / 128;
  const int ET = in_sizes[16] / 2;
  const int* srcp = ei;
  const int* dstp = ei + ET;
  float* out = (float*)d_out;

  // workspace carve-up
  size_t NB = (size_t)N_ * 128 * sizeof(float);
  char* p = (char*)d_ws;
  float* bufA = (float*)p;      p += NB;
  float* bufB = (float*)p;      p += NB;
  float* es = (float*)p;        p += (size_t)N_ * 4 * sizeof(float);
  float* ed = (float*)p;        p += (size_t)N_ * 4 * sizeof(float);
  int* cnt = (int*)p;           p += (size_t)N_ * sizeof(int);
  int* row_ptr = (int*)p;       p += (size_t)(N_ + 1) * sizeof(int);
  int* cursor = (int*)p;        p += (size_t)N_ * sizeof(int);
  int* bsum = (int*)p;          p += (size_t)((N_ + 255) / 256) * sizeof(int);
  int* csr_src = (int*)p;       p += (size_t)ET * sizeof(int);

  dim3 b256(256);
  int gGemm = (N_ + 31) / 32;
  int gNode = (N_ + 255) / 256;
  int gEdge = (ET + 255) / 256;
  int gAggr = (N_ + 3) / 4;
  int nb = (N_ + 255) / 256;

  // ---- CSR build (edge_index shared by all 3 layers) ----
  hipMemsetAsync(cnt, 0, (size_t)N_ * sizeof(int), stream);
  count_k<<<gEdge, b256, 0, stream>>>(dstp, cnt, ET);
  block_scan_k<<<nb, b256, 0, stream>>>(cnt, row_ptr, bsum, N_);
  bsum_scan_k<<<1, 64, 0, stream>>>(bsum, nb);
  add_off_k<<<gNode, b256, 0, stream>>>(row_ptr, bsum, N_, ET);
  hipMemcpyAsync(cursor, row_ptr, (size_t)N_ * sizeof(int),
                 hipMemcpyDeviceToDevice, stream);
  fill_k<<<gEdge, b256, 0, stream>>>(srcp, dstp, cursor, csr_src, ET);

  // encode: bufA = x @ enc_w + enc_b
  gemm_k<128, true><<<gGemm, b256, 0, stream>>>(x, encw, encb, bufA, N_);

  // ---- layer 1 (4 heads x 32) ----
  gemm_k<128, false><<<gGemm, b256, 0, stream>>>(bufA, W1, nullptr, bufB, N_);
  attn_coef_k<4, 32><<<gNode, b256, 0, stream>>>(bufB, as1, ad1, es, ed, N_);
  aggr_csr_k<4, 32, true><<<gAggr, b256, 0, stream>>>(bufB, es, ed, row_ptr,
                                                      csr_src, b1, bufA, N_);

  // ---- layer 2 (4 heads x 32) ----
  gemm_k<128, false><<<gGemm, b256, 0, stream>>>(bufA, W2, nullptr, bufB, N_);
  attn_coef_k<4, 32><<<gNode, b256, 0, stream>>>(bufB, as2, ad2, es, ed, N_);
  aggr_csr_k<4, 32, true><<<gAggr, b256, 0, stream>>>(bufB, es, ed, row_ptr,
                                                      csr_src, b2, bufA, N_);

  // ---- layer 3 (1 head x 64) -> d_out ----
  gemm_k<64, false><<<gGemm, b256, 0, stream>>>(bufA, W3, nullptr, bufB, N_);
  attn_coef_k<1, 64><<<gNode, b256, 0, stream>>>(bufB, as3, ad3, es, ed, N_);
  aggr_csr_k<1, 64, false><<<gAggr, b256, 0, stream>>>(bufB, es, ed, row_ptr,
                                                       csr_src, b3, out, N_);
}

// Round 4
// 968.600 us; speedup vs baseline: 5.1307x; 1.1318x over previous
//
#include <hip/hip_runtime.h>

// GAT via device-built CSR. Fused per-dst segment softmax + aggregation:
// phase1 stage v=lrelu(es+ed) in LDS + max, phase2 ex=exp(v-m) in LDS + den,
// phase3 unnormalized float4 accumulate (EPI edges/iter), normalize at end.

__device__ __forceinline__ float lrelu(float v) { return v >= 0.f ? v : 0.2f * v; }

// ---------------- GEMM: Y[n,OUTC] = X[n,128] @ W[128,OUTC] (+bias) ----------------
template <int OUTC, bool BIAS>
__global__ __launch_bounds__(256) void gemm_k(const float* __restrict__ X,
                                              const float* __restrict__ W,
                                              const float* __restrict__ B,
                                              float* __restrict__ Y, int n) {
  __shared__ float sW[128 * OUTC];
  __shared__ float sX[32 * 128];
  for (int i = threadIdx.x * 4; i < 128 * OUTC; i += 256 * 4)
    *(float4*)&sW[i] = *(const float4*)&W[i];
  int row0 = blockIdx.x * 32;
  for (int i = threadIdx.x * 4; i < 32 * 128; i += 256 * 4) {
    int r = i >> 7, c = i & 127;
    int gr = row0 + r;
    float4 v = make_float4(0.f, 0.f, 0.f, 0.f);
    if (gr < n) v = *(const float4*)&X[(size_t)gr * 128 + c];
    *(float4*)&sX[i] = v;
  }
  __syncthreads();
  const int tx = threadIdx.x & 31;
  const int ty = threadIdx.x >> 5;
  constexpr int CPT = OUTC / 32;
  const int c0 = tx * CPT;
  const int r0 = ty * 4;
  float acc[4][CPT];
#pragma unroll
  for (int r = 0; r < 4; r++)
#pragma unroll
    for (int c = 0; c < CPT; c++) acc[r][c] = 0.f;

  for (int k = 0; k < 128; k += 4) {
    float4 xv0 = *(float4*)&sX[(r0 + 0) * 128 + k];
    float4 xv1 = *(float4*)&sX[(r0 + 1) * 128 + k];
    float4 xv2 = *(float4*)&sX[(r0 + 2) * 128 + k];
    float4 xv3 = *(float4*)&sX[(r0 + 3) * 128 + k];
#pragma unroll
    for (int kk = 0; kk < 4; kk++) {
      float w[CPT];
#pragma unroll
      for (int c = 0; c < CPT; c++) w[c] = sW[(k + kk) * OUTC + c0 + c];
      float x0 = (&xv0.x)[kk], x1 = (&xv1.x)[kk], x2 = (&xv2.x)[kk], x3 = (&xv3.x)[kk];
#pragma unroll
      for (int c = 0; c < CPT; c++) {
        acc[0][c] = fmaf(x0, w[c], acc[0][c]);
        acc[1][c] = fmaf(x1, w[c], acc[1][c]);
        acc[2][c] = fmaf(x2, w[c], acc[2][c]);
        acc[3][c] = fmaf(x3, w[c], acc[3][c]);
      }
    }
  }
#pragma unroll
  for (int r = 0; r < 4; r++) {
    int gr = row0 + r0 + r;
    if (gr < n) {
#pragma unroll
      for (int c = 0; c < CPT; c++) {
        float v = acc[r][c];
        if (BIAS) v += B[c0 + c];
        Y[(size_t)gr * OUTC + c0 + c] = v;
      }
    }
  }
}

// ---------------- per-node attention coefficients ----------------
template <int NH, int CH>
__global__ __launch_bounds__(256) void attn_coef_k(const float* __restrict__ H,
                                                   const float* __restrict__ AS,
                                                   const float* __restrict__ AD,
                                                   float* __restrict__ es,
                                                   float* __restrict__ ed, int n) {
  int nidx = blockIdx.x * 256 + threadIdx.x;
  if (nidx >= n) return;
  const float* h = H + (size_t)nidx * (NH * CH);
#pragma unroll
  for (int hh = 0; hh < NH; hh++) {
    float s = 0.f, d = 0.f;
#pragma unroll
    for (int c = 0; c < CH; c += 4) {
      float4 hv = *(const float4*)&h[hh * CH + c];
      float4 av = *(const float4*)&AS[hh * CH + c];
      float4 dv = *(const float4*)&AD[hh * CH + c];
      s += hv.x * av.x + hv.y * av.y + hv.z * av.z + hv.w * av.w;
      d += hv.x * dv.x + hv.y * dv.y + hv.z * dv.z + hv.w * dv.w;
    }
    es[(size_t)nidx * NH + hh] = s;
    ed[(size_t)nidx * NH + hh] = d;
  }
}

// ---------------- CSR build ----------------
__global__ __launch_bounds__(256) void count_k(const int* __restrict__ dst,
                                               int* __restrict__ cnt, int ET) {
  int e = blockIdx.x * 256 + threadIdx.x;
  if (e < ET) atomicAdd(&cnt[dst[e]], 1);
}

__global__ __launch_bounds__(256) void block_scan_k(const int* __restrict__ cnt,
                                                    int* __restrict__ row_ptr,
                                                    int* __restrict__ bsum, int n) {
  __shared__ int s[256];
  int t = threadIdx.x;
  int idx = blockIdx.x * 256 + t;
  int val = (idx < n) ? cnt[idx] : 0;
  s[t] = val;
  __syncthreads();
  for (int off = 1; off < 256; off <<= 1) {
    int x = (t >= off) ? s[t - off] : 0;
    __syncthreads();
    s[t] += x;
    __syncthreads();
  }
  if (idx < n) row_ptr[idx] = s[t] - val;  // exclusive
  if (t == 255) bsum[blockIdx.x] = s[255];
}

__global__ void bsum_scan_k(int* __restrict__ bsum, int nb) {
  if (blockIdx.x == 0 && threadIdx.x == 0) {
    int run = 0;
    for (int i = 0; i < nb; i++) {
      int v = bsum[i];
      bsum[i] = run;
      run += v;
    }
  }
}

__global__ __launch_bounds__(256) void add_off_k(int* __restrict__ row_ptr,
                                                 const int* __restrict__ bsum,
                                                 int n, int ET) {
  int idx = blockIdx.x * 256 + threadIdx.x;
  if (idx < n) row_ptr[idx] += bsum[idx >> 8];
  if (idx == 0) row_ptr[n] = ET;
}

__global__ __launch_bounds__(256) void fill_k(const int* __restrict__ src,
                                              const int* __restrict__ dst,
                                              int* __restrict__ cursor,
                                              int* __restrict__ csr_src, int ET) {
  int e = blockIdx.x * 256 + threadIdx.x;
  if (e >= ET) return;
  int pos = atomicAdd(&cursor[dst[e]], 1);
  csr_src[pos] = src[e];
}

// ---------------- fused segment softmax + aggregation (one wave / dst) --------
template <int NH, int CH, bool RELU>
__global__ __launch_bounds__(256) void aggr_csr_k(const float* __restrict__ H,
                                                  const float* __restrict__ es,
                                                  const float* __restrict__ ed,
                                                  const int* __restrict__ row_ptr,
                                                  const int* __restrict__ csr_src,
                                                  const float* __restrict__ bias,
                                                  float* __restrict__ out, int n) {
  constexpr int NC = NH * CH;      // 128 or 64
  constexpr int QPR = NC / 4;      // float4 quads per row: 32 or 16
  constexpr int EPI = 64 / QPR;    // edges per phase-3 iter: 2 or 4
  constexpr int CAP = 128;
  __shared__ int sE[4][CAP];
  __shared__ float sA[4][NH][CAP];

  const int w = threadIdx.x >> 6;
  const int d = blockIdx.x * 4 + w;
  if (d >= n) return;
  const int lane = threadIdx.x & 63;
  const int beg = row_ptr[d];
  const int deg = row_ptr[d + 1] - beg;

  float edv[NH];
#pragma unroll
  for (int h = 0; h < NH; h++) edv[h] = ed[(size_t)d * NH + h];

  // v = lrelu(es[s] + ed[d]) per head
  auto compute_v = [&](int s, float* v) {
    if constexpr (NH == 4) {
      float4 e4 = *(const float4*)&es[(size_t)s * 4];
      v[0] = lrelu(e4.x + edv[0]);
      v[1] = lrelu(e4.y + edv[1]);
      v[2] = lrelu(e4.z + edv[2]);
      v[3] = lrelu(e4.w + edv[3]);
    } else {
      v[0] = lrelu(es[s] + edv[0]);
    }
  };
  auto pick = [&](const float (&arr)[NH], int h) -> float {
    if constexpr (NH == 1) return arr[0];
    else return (h == 0) ? arr[0] : (h == 1) ? arr[1] : (h == 2) ? arr[2] : arr[3];
  };

  // ---- phase 1: stage src + v into LDS, per-head max ----
  float mx[NH];
#pragma unroll
  for (int h = 0; h < NH; h++) mx[h] = -INFINITY;
  for (int i = lane; i < deg; i += 64) {
    int s = csr_src[beg + i];
    if (i < CAP) sE[w][i] = s;
    float v[NH];
    compute_v(s, v);
#pragma unroll
    for (int h = 0; h < NH; h++) {
      if (i < CAP) sA[w][h][i] = v[h];
      mx[h] = fmaxf(mx[h], v[h]);
    }
  }
  __builtin_amdgcn_wave_barrier();
#pragma unroll
  for (int off = 32; off; off >>= 1)
#pragma unroll
    for (int h = 0; h < NH; h++) mx[h] = fmaxf(mx[h], __shfl_xor(mx[h], off, 64));

  // ---- phase 2: ex = exp(v - m) into LDS, denominators ----
  float den[NH];
#pragma unroll
  for (int h = 0; h < NH; h++) den[h] = 0.f;
  for (int i = lane; i < deg; i += 64) {
    float v[NH];
    if (i < CAP) {
#pragma unroll
      for (int h = 0; h < NH; h++) v[h] = sA[w][h][i];
    } else {
      compute_v(csr_src[beg + i], v);
    }
#pragma unroll
    for (int h = 0; h < NH; h++) {
      float ex = __expf(v[h] - mx[h]);
      if (i < CAP) sA[w][h][i] = ex;
      den[h] += ex;
    }
  }
  __builtin_amdgcn_wave_barrier();
#pragma unroll
  for (int off = 32; off; off >>= 1)
#pragma unroll
    for (int h = 0; h < NH; h++) den[h] += __shfl_xor(den[h], off, 64);

  // ---- phase 3: unnormalized accumulate, EPI edges per iteration ----
  const int gl = lane % QPR;          // channel quad
  const int grp = lane / QPR;         // edge offset within iter
  const int head = (gl * 4) / CH;     // compile-time-reducible (CH=64 -> 0)
  float4 acc = make_float4(0.f, 0.f, 0.f, 0.f);
  for (int i = 0; i < deg; i += EPI) {
    int idx = i + grp;
    if (idx < deg) {
      int s;
      float ex;
      if (idx < CAP) {
        s = sE[w][idx];
        ex = sA[w][head][idx];
      } else {
        s = csr_src[beg + idx];
        float v[NH];
        compute_v(s, v);
        ex = __expf(pick(v, head) - pick(mx, head));
      }
      float4 hv = *(const float4*)&H[(size_t)s * NC + gl * 4];
      acc.x = fmaf(hv.x, ex, acc.x);
      acc.y = fmaf(hv.y, ex, acc.y);
      acc.z = fmaf(hv.z, ex, acc.z);
      acc.w = fmaf(hv.w, ex, acc.w);
    }
  }
  // reduce across edge groups (lanes gl, gl+QPR, ...)
#pragma unroll
  for (int off = 32; off >= QPR; off >>= 1) {
    acc.x += __shfl_xor(acc.x, off, 64);
    acc.y += __shfl_xor(acc.y, off, 64);
    acc.z += __shfl_xor(acc.z, off, 64);
    acc.w += __shfl_xor(acc.w, off, 64);
  }
  if (grp == 0) {
    float inv = 1.f / pick(den, head);
    float4 bv = *(const float4*)&bias[gl * 4];
    float4 o;
    o.x = fmaf(acc.x, inv, bv.x);
    o.y = fmaf(acc.y, inv, bv.y);
    o.z = fmaf(acc.z, inv, bv.z);
    o.w = fmaf(acc.w, inv, bv.w);
    if (RELU) {
      o.x = fmaxf(o.x, 0.f); o.y = fmaxf(o.y, 0.f);
      o.z = fmaxf(o.z, 0.f); o.w = fmaxf(o.w, 0.f);
    }
    *(float4*)&out[(size_t)d * NC + gl * 4] = o;
  }
}

extern "C" void kernel_launch(void* const* d_in, const int* in_sizes, int n_in,
                              void* d_out, int out_size, void* d_ws, size_t ws_size,
                              hipStream_t stream) {
  const float* x = (const float*)d_in[0];
  const float* encw = (const float*)d_in[2];
  const float* encb = (const float*)d_in[3];
  const float* W1 = (const float*)d_in[4];
  const float* as1 = (const float*)d_in[5];
  const float* ad1 = (const float*)d_in[6];
  const float* b1 = (const float*)d_in[7];
  const float* W2 = (const float*)d_in[8];
  const float* as2 = (const float*)d_in[9];
  const float* ad2 = (const float*)d_in[10];
  const float* b2 = (const float*)d_in[11];
  const float* W3 = (const float*)d_in[12];
  const float* as3 = (const float*)d_in[13];
  const float* ad3 = (const float*)d_in[14];
  const float* b3 = (const float*)d_in[15];
  const int* ei = (const int*)d_in[16];

  const int N_ = in_sizes[0] / 128;
  const int ET = in_sizes[16] / 2;
  const int* srcp = ei;
  const int* dstp = ei + ET;
  float* out = (float*)d_out;

  // workspace carve-up
  size_t NB = (size_t)N_ * 128 * sizeof(float);
  char* p = (char*)d_ws;
  float* bufA = (float*)p;      p += NB;
  float* bufB = (float*)p;      p += NB;
  float* es = (float*)p;        p += (size_t)N_ * 4 * sizeof(float);
  float* ed = (float*)p;        p += (size_t)N_ * 4 * sizeof(float);
  int* cnt = (int*)p;           p += (size_t)N_ * sizeof(int);
  int* row_ptr = (int*)p;       p += (size_t)(N_ + 1) * sizeof(int);
  int* cursor = (int*)p;        p += (size_t)N_ * sizeof(int);
  int* bsum = (int*)p;          p += (size_t)((N_ + 255) / 256) * sizeof(int);
  int* csr_src = (int*)p;       p += (size_t)ET * sizeof(int);

  dim3 b256(256);
  int gGemm = (N_ + 31) / 32;
  int gNode = (N_ + 255) / 256;
  int gEdge = (ET + 255) / 256;
  int gAggr = (N_ + 3) / 4;
  int nb = (N_ + 255) / 256;

  // ---- CSR build (edge_index shared by all 3 layers) ----
  hipMemsetAsync(cnt, 0, (size_t)N_ * sizeof(int), stream);
  count_k<<<gEdge, b256, 0, stream>>>(dstp, cnt, ET);
  block_scan_k<<<nb, b256, 0, stream>>>(cnt, row_ptr, bsum, N_);
  bsum_scan_k<<<1, 64, 0, stream>>>(bsum, nb);
  add_off_k<<<gNode, b256, 0, stream>>>(row_ptr, bsum, N_, ET);
  hipMemcpyAsync(cursor, row_ptr, (size_t)N_ * sizeof(int),
                 hipMemcpyDeviceToDevice, stream);
  fill_k<<<gEdge, b256, 0, stream>>>(srcp, dstp, cursor, csr_src, ET);

  // encode: bufA = x @ enc_w + enc_b
  gemm_k<128, true><<<gGemm, b256, 0, stream>>>(x, encw, encb, bufA, N_);

  // ---- layer 1 (4 heads x 32) ----
  gemm_k<128, false><<<gGemm, b256, 0, stream>>>(bufA, W1, nullptr, bufB, N_);
  attn_coef_k<4, 32><<<gNode, b256, 0, stream>>>(bufB, as1, ad1, es, ed, N_);
  aggr_csr_k<4, 32, true><<<gAggr, b256, 0, stream>>>(bufB, es, ed, row_ptr,
                                                      csr_src, b1, bufA, N_);

  // ---- layer 2 (4 heads x 32) ----
  gemm_k<128, false><<<gGemm, b256, 0, stream>>>(bufA, W2, nullptr, bufB, N_);
  attn_coef_k<4, 32><<<gNode, b256, 0, stream>>>(bufB, as2, ad2, es, ed, N_);
  aggr_csr_k<4, 32, true><<<gAggr, b256, 0, stream>>>(bufB, es, ed, row_ptr,
                                                      csr_src, b2, bufA, N_);

  // ---- layer 3 (1 head x 64) -> d_out ----
  gemm_k<64, false><<<gGemm, b256, 0, stream>>>(bufA, W3, nullptr, bufB, N_);
  attn_coef_k<1, 64><<<gNode, b256, 0, stream>>>(bufB, as3, ad3, es, ed, N_);
  aggr_csr_k<1, 64, false><<<gAggr, b256, 0, stream>>>(bufB, es, ed, row_ptr,
                                                       csr_src, b3, out, N_);
}

// Round 6
// 953.577 us; speedup vs baseline: 5.2115x; 1.0158x over previous
//
#include <hip/hip_runtime.h>

// GAT via device-built CSR. Aggregation is 2 passes per dst-wave:
// pass1: stage src+v(edge-major) in LDS, shuffle max-reduce.
// pass2: fused exp/den/accumulate (den reduced in the same shuffle as acc).

__device__ __forceinline__ float lrelu(float v) { return v >= 0.f ? v : 0.2f * v; }

// ---------------- GEMM: Y[n,OUTC] = X[n,128] @ W[128,OUTC] (+bias) ----------------
template <int OUTC, bool BIAS>
__global__ __launch_bounds__(256) void gemm_k(const float* __restrict__ X,
                                              const float* __restrict__ W,
                                              const float* __restrict__ B,
                                              float* __restrict__ Y, int n) {
  __shared__ float sW[128 * OUTC];
  __shared__ float sX[32 * 128];
  for (int i = threadIdx.x * 4; i < 128 * OUTC; i += 256 * 4)
    *(float4*)&sW[i] = *(const float4*)&W[i];
  int row0 = blockIdx.x * 32;
  for (int i = threadIdx.x * 4; i < 32 * 128; i += 256 * 4) {
    int r = i >> 7, c = i & 127;
    int gr = row0 + r;
    float4 v = make_float4(0.f, 0.f, 0.f, 0.f);
    if (gr < n) v = *(const float4*)&X[(size_t)gr * 128 + c];
    *(float4*)&sX[i] = v;
  }
  __syncthreads();
  const int tx = threadIdx.x & 31;
  const int ty = threadIdx.x >> 5;
  constexpr int CPT = OUTC / 32;
  const int c0 = tx * CPT;
  const int r0 = ty * 4;
  float acc[4][CPT];
#pragma unroll
  for (int r = 0; r < 4; r++)
#pragma unroll
    for (int c = 0; c < CPT; c++) acc[r][c] = 0.f;

  for (int k = 0; k < 128; k += 4) {
    float4 xv0 = *(float4*)&sX[(r0 + 0) * 128 + k];
    float4 xv1 = *(float4*)&sX[(r0 + 1) * 128 + k];
    float4 xv2 = *(float4*)&sX[(r0 + 2) * 128 + k];
    float4 xv3 = *(float4*)&sX[(r0 + 3) * 128 + k];
#pragma unroll
    for (int kk = 0; kk < 4; kk++) {
      float w[CPT];
#pragma unroll
      for (int c = 0; c < CPT; c++) w[c] = sW[(k + kk) * OUTC + c0 + c];
      float x0 = (&xv0.x)[kk], x1 = (&xv1.x)[kk], x2 = (&xv2.x)[kk], x3 = (&xv3.x)[kk];
#pragma unroll
      for (int c = 0; c < CPT; c++) {
        acc[0][c] = fmaf(x0, w[c], acc[0][c]);
        acc[1][c] = fmaf(x1, w[c], acc[1][c]);
        acc[2][c] = fmaf(x2, w[c], acc[2][c]);
        acc[3][c] = fmaf(x3, w[c], acc[3][c]);
      }
    }
  }
#pragma unroll
  for (int r = 0; r < 4; r++) {
    int gr = row0 + r0 + r;
    if (gr < n) {
#pragma unroll
      for (int c = 0; c < CPT; c++) {
        float v = acc[r][c];
        if (BIAS) v += B[c0 + c];
        Y[(size_t)gr * OUTC + c0 + c] = v;
      }
    }
  }
}

// ---------------- per-node attention coefficients ----------------
template <int NH, int CH>
__global__ __launch_bounds__(256) void attn_coef_k(const float* __restrict__ H,
                                                   const float* __restrict__ AS,
                                                   const float* __restrict__ AD,
                                                   float* __restrict__ es,
                                                   float* __restrict__ ed, int n) {
  int nidx = blockIdx.x * 256 + threadIdx.x;
  if (nidx >= n) return;
  const float* h = H + (size_t)nidx * (NH * CH);
#pragma unroll
  for (int hh = 0; hh < NH; hh++) {
    float s = 0.f, d = 0.f;
#pragma unroll
    for (int c = 0; c < CH; c += 4) {
      float4 hv = *(const float4*)&h[hh * CH + c];
      float4 av = *(const float4*)&AS[hh * CH + c];
      float4 dv = *(const float4*)&AD[hh * CH + c];
      s += hv.x * av.x + hv.y * av.y + hv.z * av.z + hv.w * av.w;
      d += hv.x * dv.x + hv.y * dv.y + hv.z * dv.z + hv.w * dv.w;
    }
    es[(size_t)nidx * NH + hh] = s;
    ed[(size_t)nidx * NH + hh] = d;
  }
}

// ---------------- CSR build ----------------
__global__ __launch_bounds__(256) void count_k(const int* __restrict__ dst,
                                               int* __restrict__ cnt, int ET) {
  int e = blockIdx.x * 256 + threadIdx.x;
  if (e < ET) atomicAdd(&cnt[dst[e]], 1);
}

__global__ __launch_bounds__(256) void block_scan_k(const int* __restrict__ cnt,
                                                    int* __restrict__ row_ptr,
                                                    int* __restrict__ bsum, int n) {
  __shared__ int s[256];
  int t = threadIdx.x;
  int idx = blockIdx.x * 256 + t;
  int val = (idx < n) ? cnt[idx] : 0;
  s[t] = val;
  __syncthreads();
  for (int off = 1; off < 256; off <<= 1) {
    int x = (t >= off) ? s[t - off] : 0;
    __syncthreads();
    s[t] += x;
    __syncthreads();
  }
  if (idx < n) row_ptr[idx] = s[t] - val;  // exclusive
  if (t == 255) bsum[blockIdx.x] = s[255];
}

__global__ void bsum_scan_k(int* __restrict__ bsum, int nb) {
  if (blockIdx.x == 0 && threadIdx.x == 0) {
    int run = 0;
    for (int i = 0; i < nb; i++) {
      int v = bsum[i];
      bsum[i] = run;
      run += v;
    }
  }
}

__global__ __launch_bounds__(256) void add_off_k(int* __restrict__ row_ptr,
                                                 const int* __restrict__ bsum,
                                                 int n, int ET) {
  int idx = blockIdx.x * 256 + threadIdx.x;
  if (idx < n) row_ptr[idx] += bsum[idx >> 8];
  if (idx == 0) row_ptr[n] = ET;
}

__global__ __launch_bounds__(256) void fill_k(const int* __restrict__ src,
                                              const int* __restrict__ dst,
                                              int* __restrict__ cursor,
                                              int* __restrict__ csr_src, int ET) {
  int e = blockIdx.x * 256 + threadIdx.x;
  if (e >= ET) return;
  int pos = atomicAdd(&cursor[dst[e]], 1);
  csr_src[pos] = src[e];
}

// ---------------- fused segment softmax + aggregation (one wave / dst) --------
template <int NH, int CH, bool RELU>
__global__ __launch_bounds__(256) void aggr_csr_k(const float* __restrict__ H,
                                                  const float* __restrict__ es,
                                                  const float* __restrict__ ed,
                                                  const int* __restrict__ row_ptr,
                                                  const int* __restrict__ csr_src,
                                                  const float* __restrict__ bias,
                                                  float* __restrict__ out, int n) {
  constexpr int NC = NH * CH;      // 128 or 64
  constexpr int QPR = NC / 4;      // float4 quads per row: 32 or 16
  constexpr int EPI = 64 / QPR;    // edges per iter: 2 or 4
  constexpr int CAP = 128;
  __shared__ int sE[4][CAP];
  __shared__ float sV[4][CAP][NH];  // edge-major: [i][h] -> conflict-free reads

  const int w = threadIdx.x >> 6;
  const int d = blockIdx.x * 4 + w;
  if (d >= n) return;
  const int lane = threadIdx.x & 63;
  const int beg = row_ptr[d];
  const int deg = row_ptr[d + 1] - beg;

  float edv[NH];
#pragma unroll
  for (int h = 0; h < NH; h++) edv[h] = ed[(size_t)d * NH + h];

  auto compute_v = [&](int s, float* v) {
    if constexpr (NH == 4) {
      float4 e4 = *(const float4*)&es[(size_t)s * 4];
      v[0] = lrelu(e4.x + edv[0]);
      v[1] = lrelu(e4.y + edv[1]);
      v[2] = lrelu(e4.z + edv[2]);
      v[3] = lrelu(e4.w + edv[3]);
    } else {
      v[0] = lrelu(es[s] + edv[0]);
    }
  };
  auto pick = [&](const float (&arr)[NH], int h) -> float {
    if constexpr (NH == 1) return arr[0];
    else return (h == 0) ? arr[0] : (h == 1) ? arr[1] : (h == 2) ? arr[2] : arr[3];
  };

  // ---- pass 1: stage src + v (edge-major) into LDS, per-head max ----
  float mx[NH];
#pragma unroll
  for (int h = 0; h < NH; h++) mx[h] = -INFINITY;
  for (int i = lane; i < deg; i += 64) {
    int s = csr_src[beg + i];
    float v[NH];
    compute_v(s, v);
    if (i < CAP) {
      sE[w][i] = s;
      if constexpr (NH == 4) {
        *(float4*)&sV[w][i][0] = make_float4(v[0], v[1], v[2], v[3]);
      } else {
        sV[w][i][0] = v[0];
      }
    }
#pragma unroll
    for (int h = 0; h < NH; h++) mx[h] = fmaxf(mx[h], v[h]);
  }
  __builtin_amdgcn_wave_barrier();
#pragma unroll
  for (int off = 32; off; off >>= 1)
#pragma unroll
    for (int h = 0; h < NH; h++) mx[h] = fmaxf(mx[h], __shfl_xor(mx[h], off, 64));

  // ---- pass 2: fused exp + den + accumulate (EPI edges per iteration) ----
  const int gl = lane % QPR;          // channel quad
  const int grp = lane / QPR;         // edge offset within iter
  const int head = (gl * 4) / CH;     // NH=1 -> 0
  const float m_h = pick(mx, head);
  float den = 0.f;
  float4 acc = make_float4(0.f, 0.f, 0.f, 0.f);

  auto body = [&](int idx) {
    int s;
    float v;
    if (idx < CAP) {
      s = sE[w][idx];
      v = sV[w][idx][(NH == 4) ? head : 0];
    } else {
      s = csr_src[beg + idx];
      float vv[NH];
      compute_v(s, vv);
      v = pick(vv, head);
    }
    float ex = __expf(v - m_h);
    den += ex;
    float4 hv = *(const float4*)&H[(size_t)s * NC + gl * 4];
    acc.x = fmaf(hv.x, ex, acc.x);
    acc.y = fmaf(hv.y, ex, acc.y);
    acc.z = fmaf(hv.z, ex, acc.z);
    acc.w = fmaf(hv.w, ex, acc.w);
  };

  int i = 0;
  for (; i + EPI <= deg; i += EPI) body(i + grp);   // unguarded main loop
  if (i + grp < deg) body(i + grp);                 // tail

  // reduce acc AND den across edge groups (lanes gl, gl+QPR, ...)
#pragma unroll
  for (int off = 32; off >= QPR; off >>= 1) {
    acc.x += __shfl_xor(acc.x, off, 64);
    acc.y += __shfl_xor(acc.y, off, 64);
    acc.z += __shfl_xor(acc.z, off, 64);
    acc.w += __shfl_xor(acc.w, off, 64);
    den   += __shfl_xor(den,   off, 64);
  }
  if (grp == 0) {
    float inv = 1.f / den;
    float4 bv = *(const float4*)&bias[gl * 4];
    float4 o;
    o.x = fmaf(acc.x, inv, bv.x);
    o.y = fmaf(acc.y, inv, bv.y);
    o.z = fmaf(acc.z, inv, bv.z);
    o.w = fmaf(acc.w, inv, bv.w);
    if (RELU) {
      o.x = fmaxf(o.x, 0.f); o.y = fmaxf(o.y, 0.f);
      o.z = fmaxf(o.z, 0.f); o.w = fmaxf(o.w, 0.f);
    }
    *(float4*)&out[(size_t)d * NC + gl * 4] = o;
  }
}

extern "C" void kernel_launch(void* const* d_in, const int* in_sizes, int n_in,
                              void* d_out, int out_size, void* d_ws, size_t ws_size,
                              hipStream_t stream) {
  const float* x = (const float*)d_in[0];
  const float* encw = (const float*)d_in[2];
  const float* encb = (const float*)d_in[3];
  const float* W1 = (const float*)d_in[4];
  const float* as1 = (const float*)d_in[5];
  const float* ad1 = (const float*)d_in[6];
  const float* b1 = (const float*)d_in[7];
  const float* W2 = (const float*)d_in[8];
  const float* as2 = (const float*)d_in[9];
  const float* ad2 = (const float*)d_in[10];
  const float* b2 = (const float*)d_in[11];
  const float* W3 = (const float*)d_in[12];
  const float* as3 = (const float*)d_in[13];
  const float* ad3 = (const float*)d_in[14];
  const float* b3 = (const float*)d_in[15];
  const int* ei = (const int*)d_in[16];

  const int N_ = in_sizes[0] / 128;
  const int ET = in_sizes[16] / 2;
  const int* srcp = ei;
  const int* dstp = ei + ET;
  float* out = (float*)d_out;

  // workspace carve-up
  size_t NB = (size_t)N_ * 128 * sizeof(float);
  char* p = (char*)d_ws;
  float* bufA = (float*)p;      p += NB;
  float* bufB = (float*)p;      p += NB;
  float* es = (float*)p;        p += (size_t)N_ * 4 * sizeof(float);
  float* ed = (float*)p;        p += (size_t)N_ * 4 * sizeof(float);
  int* cnt = (int*)p;           p += (size_t)N_ * sizeof(int);
  int* row_ptr = (int*)p;       p += (size_t)(N_ + 1) * sizeof(int);
  int* cursor = (int*)p;        p += (size_t)N_ * sizeof(int);
  int* bsum = (int*)p;          p += (size_t)((N_ + 255) / 256) * sizeof(int);
  int* csr_src = (int*)p;       p += (size_t)ET * sizeof(int);

  dim3 b256(256);
  int gGemm = (N_ + 31) / 32;
  int gNode = (N_ + 255) / 256;
  int gEdge = (ET + 255) / 256;
  int gAggr = (N_ + 3) / 4;
  int nb = (N_ + 255) / 256;

  // ---- CSR build (edge_index shared by all 3 layers) ----
  hipMemsetAsync(cnt, 0, (size_t)N_ * sizeof(int), stream);
  count_k<<<gEdge, b256, 0, stream>>>(dstp, cnt, ET);
  block_scan_k<<<nb, b256, 0, stream>>>(cnt, row_ptr, bsum, N_);
  bsum_scan_k<<<1, 64, 0, stream>>>(bsum, nb);
  add_off_k<<<gNode, b256, 0, stream>>>(row_ptr, bsum, N_, ET);
  hipMemcpyAsync(cursor, row_ptr, (size_t)N_ * sizeof(int),
                 hipMemcpyDeviceToDevice, stream);
  fill_k<<<gEdge, b256, 0, stream>>>(srcp, dstp, cursor, csr_src, ET);

  // encode: bufA = x @ enc_w + enc_b
  gemm_k<128, true><<<gGemm, b256, 0, stream>>>(x, encw, encb, bufA, N_);

  // ---- layer 1 (4 heads x 32) ----
  gemm_k<128, false><<<gGemm, b256, 0, stream>>>(bufA, W1, nullptr, bufB, N_);
  attn_coef_k<4, 32><<<gNode, b256, 0, stream>>>(bufB, as1, ad1, es, ed, N_);
  aggr_csr_k<4, 32, true><<<gAggr, b256, 0, stream>>>(bufB, es, ed, row_ptr,
                                                      csr_src, b1, bufA, N_);

  // ---- layer 2 (4 heads x 32) ----
  gemm_k<128, false><<<gGemm, b256, 0, stream>>>(bufA, W2, nullptr, bufB, N_);
  attn_coef_k<4, 32><<<gNode, b256, 0, stream>>>(bufB, as2, ad2, es, ed, N_);
  aggr_csr_k<4, 32, true><<<gAggr, b256, 0, stream>>>(bufB, es, ed, row_ptr,
                                                      csr_src, b2, bufA, N_);

  // ---- layer 3 (1 head x 64) -> d_out ----
  gemm_k<64, false><<<gGemm, b256, 0, stream>>>(bufA, W3, nullptr, bufB, N_);
  attn_coef_k<1, 64><<<gNode, b256, 0, stream>>>(bufB, as3, ad3, es, ed, N_);
  aggr_csr_k<1, 64, false><<<gAggr, b256, 0, stream>>>(bufB, es, ed, row_ptr,
                                                       csr_src, b3, out, N_);
}

// Round 7
// 895.780 us; speedup vs baseline: 5.5477x; 1.0645x over previous
//
#include <hip/hip_runtime.h>

// GAT via device-built CSR. es/ed fused into GEMM epilogue; aggregation uses
// 16-lane channel groups (4 edges in flight) + depth-2 software pipeline.

__device__ __forceinline__ float lrelu(float v) { return v >= 0.f ? v : 0.2f * v; }

// ------- GEMM: Y[n,OUTC] = X[n,128] @ W[128,OUTC] (+bias) (+es/ed epilogue) -------
// NH=0: no coef epilogue. NH>0: es/ed[n,NH] from a_src/a_dst dot output rows.
template <int OUTC, bool BIAS, int NH>
__global__ __launch_bounds__(256) void gemm_k(const float* __restrict__ X,
                                              const float* __restrict__ W,
                                              const float* __restrict__ B,
                                              const float* __restrict__ AS,
                                              const float* __restrict__ AD,
                                              float* __restrict__ es,
                                              float* __restrict__ ed,
                                              float* __restrict__ Y, int n) {
  __shared__ float sW[128 * OUTC];
  __shared__ float sX[32 * 128];
  for (int i = threadIdx.x * 4; i < 128 * OUTC; i += 256 * 4)
    *(float4*)&sW[i] = *(const float4*)&W[i];
  int row0 = blockIdx.x * 32;
  for (int i = threadIdx.x * 4; i < 32 * 128; i += 256 * 4) {
    int r = i >> 7, c = i & 127;
    int gr = row0 + r;
    float4 v = make_float4(0.f, 0.f, 0.f, 0.f);
    if (gr < n) v = *(const float4*)&X[(size_t)gr * 128 + c];
    *(float4*)&sX[i] = v;
  }
  __syncthreads();
  const int tx = threadIdx.x & 31;
  const int ty = threadIdx.x >> 5;
  constexpr int CPT = OUTC / 32;
  const int c0 = tx * CPT;
  const int r0 = ty * 4;
  float acc[4][CPT];
#pragma unroll
  for (int r = 0; r < 4; r++)
#pragma unroll
    for (int c = 0; c < CPT; c++) acc[r][c] = 0.f;

  for (int k = 0; k < 128; k += 4) {
    float4 xv0 = *(float4*)&sX[(r0 + 0) * 128 + k];
    float4 xv1 = *(float4*)&sX[(r0 + 1) * 128 + k];
    float4 xv2 = *(float4*)&sX[(r0 + 2) * 128 + k];
    float4 xv3 = *(float4*)&sX[(r0 + 3) * 128 + k];
#pragma unroll
    for (int kk = 0; kk < 4; kk++) {
      float w[CPT];
#pragma unroll
      for (int c = 0; c < CPT; c++) w[c] = sW[(k + kk) * OUTC + c0 + c];
      float x0 = (&xv0.x)[kk], x1 = (&xv1.x)[kk], x2 = (&xv2.x)[kk], x3 = (&xv3.x)[kk];
#pragma unroll
      for (int c = 0; c < CPT; c++) {
        acc[0][c] = fmaf(x0, w[c], acc[0][c]);
        acc[1][c] = fmaf(x1, w[c], acc[1][c]);
        acc[2][c] = fmaf(x2, w[c], acc[2][c]);
        acc[3][c] = fmaf(x3, w[c], acc[3][c]);
      }
    }
  }
#pragma unroll
  for (int r = 0; r < 4; r++) {
    int gr = row0 + r0 + r;
    if (gr < n) {
#pragma unroll
      for (int c = 0; c < CPT; c++) {
        float v = acc[r][c];
        if (BIAS) v += B[c0 + c];
        Y[(size_t)gr * OUTC + c0 + c] = v;
      }
    }
  }
  // ---- fused attention-coefficient epilogue ----
  if constexpr (NH > 0) {
    constexpr int CH = OUTC / NH;
    constexpr int GRP = CH / CPT;  // lanes per head group (8 or 32)
    float asv[CPT], adv[CPT];
#pragma unroll
    for (int c = 0; c < CPT; c++) { asv[c] = AS[c0 + c]; adv[c] = AD[c0 + c]; }
#pragma unroll
    for (int r = 0; r < 4; r++) {
      float ps = 0.f, pd = 0.f;
#pragma unroll
      for (int c = 0; c < CPT; c++) {
        ps = fmaf(acc[r][c], asv[c], ps);
        pd = fmaf(acc[r][c], adv[c], pd);
      }
#pragma unroll
      for (int off = 1; off < GRP; off <<= 1) {
        ps += __shfl_xor(ps, off, 64);
        pd += __shfl_xor(pd, off, 64);
      }
      int gr = row0 + r0 + r;
      if (gr < n && (tx & (GRP - 1)) == 0) {
        int hh = tx / GRP;
        es[(size_t)gr * NH + hh] = ps;
        ed[(size_t)gr * NH + hh] = pd;
      }
    }
  }
}

// ---------------- CSR build ----------------
__global__ __launch_bounds__(256) void count_k(const int* __restrict__ dst,
                                               int* __restrict__ cnt, int ET) {
  int e = blockIdx.x * 256 + threadIdx.x;
  if (e < ET) atomicAdd(&cnt[dst[e]], 1);
}

__global__ __launch_bounds__(256) void block_scan_k(const int* __restrict__ cnt,
                                                    int* __restrict__ row_ptr,
                                                    int* __restrict__ bsum, int n) {
  __shared__ int s[256];
  int t = threadIdx.x;
  int idx = blockIdx.x * 256 + t;
  int val = (idx < n) ? cnt[idx] : 0;
  s[t] = val;
  __syncthreads();
  for (int off = 1; off < 256; off <<= 1) {
    int x = (t >= off) ? s[t - off] : 0;
    __syncthreads();
    s[t] += x;
    __syncthreads();
  }
  if (idx < n) row_ptr[idx] = s[t] - val;  // exclusive
  if (t == 255) bsum[blockIdx.x] = s[255];
}

// single-block parallel exclusive scan of bsum (nb <= 512 for N <= 131k)
__global__ __launch_bounds__(512) void bsum_scan_k(int* __restrict__ bsum, int nb) {
  __shared__ int s[512];
  int t = threadIdx.x;
  int v = (t < nb) ? bsum[t] : 0;
  s[t] = v;
  __syncthreads();
  for (int off = 1; off < 512; off <<= 1) {
    int x = (t >= off) ? s[t - off] : 0;
    __syncthreads();
    s[t] += x;
    __syncthreads();
  }
  if (t < nb) bsum[t] = s[t] - v;  // exclusive
}

__global__ __launch_bounds__(256) void add_off_k(int* __restrict__ row_ptr,
                                                 const int* __restrict__ bsum,
                                                 int n, int ET) {
  int idx = blockIdx.x * 256 + threadIdx.x;
  if (idx < n) row_ptr[idx] += bsum[idx >> 8];
  if (idx == 0) row_ptr[n] = ET;
}

__global__ __launch_bounds__(256) void fill_k(const int* __restrict__ src,
                                              const int* __restrict__ dst,
                                              int* __restrict__ cursor,
                                              int* __restrict__ csr_src, int ET) {
  int e = blockIdx.x * 256 + threadIdx.x;
  if (e >= ET) return;
  int pos = atomicAdd(&cursor[dst[e]], 1);
  csr_src[pos] = src[e];
}

// ---------------- fused segment softmax + aggregation (one wave / dst) --------
// 16-lane channel groups -> 4 edges in flight per iteration; depth-2 pipeline.
template <int NH, int CH, bool RELU>
__global__ __launch_bounds__(256) void aggr_csr_k(const float* __restrict__ H,
                                                  const float* __restrict__ es,
                                                  const float* __restrict__ ed,
                                                  const int* __restrict__ row_ptr,
                                                  const int* __restrict__ csr_src,
                                                  const float* __restrict__ bias,
                                                  float* __restrict__ out, int n) {
  constexpr int NC = NH * CH;       // 128 or 64
  constexpr int QPR = 16;           // lanes per channel group
  constexpr int FPL = NC / QPR / 4; // float4 per lane: 2 or 1
  constexpr int EPI = 64 / QPR;     // 4 edges in flight
  constexpr int CAP = 128;
  __shared__ int sE[4][CAP];
  __shared__ float sV[4][CAP][NH];  // edge-major

  const int w = threadIdx.x >> 6;
  const int d = blockIdx.x * 4 + w;
  if (d >= n) return;
  const int lane = threadIdx.x & 63;
  const int beg = row_ptr[d];
  const int deg = row_ptr[d + 1] - beg;

  float edv[NH];
#pragma unroll
  for (int h = 0; h < NH; h++) edv[h] = ed[(size_t)d * NH + h];

  auto compute_v = [&](int s, float* v) {
    if constexpr (NH == 4) {
      float4 e4 = *(const float4*)&es[(size_t)s * 4];
      v[0] = lrelu(e4.x + edv[0]);
      v[1] = lrelu(e4.y + edv[1]);
      v[2] = lrelu(e4.z + edv[2]);
      v[3] = lrelu(e4.w + edv[3]);
    } else {
      v[0] = lrelu(es[s] + edv[0]);
    }
  };
  auto pick = [&](const float (&arr)[NH], int h) -> float {
    if constexpr (NH == 1) return arr[0];
    else return (h == 0) ? arr[0] : (h == 1) ? arr[1] : (h == 2) ? arr[2] : arr[3];
  };

  // ---- pass 1: stage src + v (edge-major) into LDS, per-head max ----
  float mx[NH];
#pragma unroll
  for (int h = 0; h < NH; h++) mx[h] = -INFINITY;
  for (int i = lane; i < deg; i += 64) {
    int s = csr_src[beg + i];
    float v[NH];
    compute_v(s, v);
    if (i < CAP) {
      sE[w][i] = s;
      if constexpr (NH == 4) {
        *(float4*)&sV[w][i][0] = make_float4(v[0], v[1], v[2], v[3]);
      } else {
        sV[w][i][0] = v[0];
      }
    }
#pragma unroll
    for (int h = 0; h < NH; h++) mx[h] = fmaxf(mx[h], v[h]);
  }
  __builtin_amdgcn_wave_barrier();
#pragma unroll
  for (int off = 32; off; off >>= 1)
#pragma unroll
    for (int h = 0; h < NH; h++) mx[h] = fmaxf(mx[h], __shfl_xor(mx[h], off, 64));

  // ---- pass 2: pipelined exp + den + accumulate (EPI edges / iteration) ----
  const int gl = lane & (QPR - 1);       // channel group slot
  const int grp = lane >> 4;             // edge offset within iter (0..3)
  const int head = (NH == 4) ? (gl >> 2) : 0;
  const int ch0 = gl * (4 * FPL);
  const float m_h = pick(mx, head);
  float den = 0.f;
  float4 acc0 = make_float4(0.f, 0.f, 0.f, 0.f);
  float4 acc1 = make_float4(0.f, 0.f, 0.f, 0.f);

  auto get_sv = [&](int idx, int& s, float& v) {
    if (idx < CAP) {
      s = sE[w][idx];
      v = sV[w][idx][head];
    } else {
      s = csr_src[beg + idx];
      float vv[NH];
      compute_v(s, vv);
      v = pick(vv, head);
    }
  };

  int i = grp;
  int sc = 0; float vc = 0.f;
  float4 h0c = make_float4(0.f, 0.f, 0.f, 0.f), h1c = h0c;
  if (i < deg) {
    get_sv(i, sc, vc);
    const float4* hp = (const float4*)&H[(size_t)sc * NC + ch0];
    h0c = hp[0];
    if constexpr (FPL == 2) h1c = hp[1];
  }
  while (i < deg) {
    int in = i + EPI;
    int sn = 0; float vn = 0.f;
    float4 h0n = make_float4(0.f, 0.f, 0.f, 0.f), h1n = h0n;
    if (in < deg) {
      get_sv(in, sn, vn);
      const float4* hp = (const float4*)&H[(size_t)sn * NC + ch0];
      h0n = hp[0];
      if constexpr (FPL == 2) h1n = hp[1];
    }
    float ex = __expf(vc - m_h);
    den += ex;
    acc0.x = fmaf(h0c.x, ex, acc0.x);
    acc0.y = fmaf(h0c.y, ex, acc0.y);
    acc0.z = fmaf(h0c.z, ex, acc0.z);
    acc0.w = fmaf(h0c.w, ex, acc0.w);
    if constexpr (FPL == 2) {
      acc1.x = fmaf(h1c.x, ex, acc1.x);
      acc1.y = fmaf(h1c.y, ex, acc1.y);
      acc1.z = fmaf(h1c.z, ex, acc1.z);
      acc1.w = fmaf(h1c.w, ex, acc1.w);
    }
    sc = sn; vc = vn; h0c = h0n;
    if constexpr (FPL == 2) h1c = h1n;
    i = in;
  }

  // reduce acc AND den across edge groups (xor 32, 16)
#pragma unroll
  for (int off = 32; off >= QPR; off >>= 1) {
    acc0.x += __shfl_xor(acc0.x, off, 64);
    acc0.y += __shfl_xor(acc0.y, off, 64);
    acc0.z += __shfl_xor(acc0.z, off, 64);
    acc0.w += __shfl_xor(acc0.w, off, 64);
    if constexpr (FPL == 2) {
      acc1.x += __shfl_xor(acc1.x, off, 64);
      acc1.y += __shfl_xor(acc1.y, off, 64);
      acc1.z += __shfl_xor(acc1.z, off, 64);
      acc1.w += __shfl_xor(acc1.w, off, 64);
    }
    den += __shfl_xor(den, off, 64);
  }
  if (grp == 0) {
    float inv = 1.f / den;
    float4 bv0 = *(const float4*)&bias[ch0];
    float4 o0;
    o0.x = fmaf(acc0.x, inv, bv0.x);
    o0.y = fmaf(acc0.y, inv, bv0.y);
    o0.z = fmaf(acc0.z, inv, bv0.z);
    o0.w = fmaf(acc0.w, inv, bv0.w);
    if (RELU) {
      o0.x = fmaxf(o0.x, 0.f); o0.y = fmaxf(o0.y, 0.f);
      o0.z = fmaxf(o0.z, 0.f); o0.w = fmaxf(o0.w, 0.f);
    }
    *(float4*)&out[(size_t)d * NC + ch0] = o0;
    if constexpr (FPL == 2) {
      float4 bv1 = *(const float4*)&bias[ch0 + 4];
      float4 o1;
      o1.x = fmaf(acc1.x, inv, bv1.x);
      o1.y = fmaf(acc1.y, inv, bv1.y);
      o1.z = fmaf(acc1.z, inv, bv1.z);
      o1.w = fmaf(acc1.w, inv, bv1.w);
      if (RELU) {
        o1.x = fmaxf(o1.x, 0.f); o1.y = fmaxf(o1.y, 0.f);
        o1.z = fmaxf(o1.z, 0.f); o1.w = fmaxf(o1.w, 0.f);
      }
      *(float4*)&out[(size_t)d * NC + ch0 + 4] = o1;
    }
  }
}

extern "C" void kernel_launch(void* const* d_in, const int* in_sizes, int n_in,
                              void* d_out, int out_size, void* d_ws, size_t ws_size,
                              hipStream_t stream) {
  const float* x = (const float*)d_in[0];
  const float* encw = (const float*)d_in[2];
  const float* encb = (const float*)d_in[3];
  const float* W1 = (const float*)d_in[4];
  const float* as1 = (const float*)d_in[5];
  const float* ad1 = (const float*)d_in[6];
  const float* b1 = (const float*)d_in[7];
  const float* W2 = (const float*)d_in[8];
  const float* as2 = (const float*)d_in[9];
  const float* ad2 = (const float*)d_in[10];
  const float* b2 = (const float*)d_in[11];
  const float* W3 = (const float*)d_in[12];
  const float* as3 = (const float*)d_in[13];
  const float* ad3 = (const float*)d_in[14];
  const float* b3 = (const float*)d_in[15];
  const int* ei = (const int*)d_in[16];

  const int N_ = in_sizes[0] / 128;
  const int ET = in_sizes[16] / 2;
  const int* srcp = ei;
  const int* dstp = ei + ET;
  float* out = (float*)d_out;

  // workspace carve-up
  size_t NB = (size_t)N_ * 128 * sizeof(float);
  char* p = (char*)d_ws;
  float* bufA = (float*)p;      p += NB;
  float* bufB = (float*)p;      p += NB;
  float* es = (float*)p;        p += (size_t)N_ * 4 * sizeof(float);
  float* ed = (float*)p;        p += (size_t)N_ * 4 * sizeof(float);
  int* cnt = (int*)p;           p += (size_t)N_ * sizeof(int);
  int* row_ptr = (int*)p;       p += (size_t)(N_ + 1) * sizeof(int);
  int* cursor = (int*)p;        p += (size_t)N_ * sizeof(int);
  int* bsum = (int*)p;          p += (size_t)((N_ + 255) / 256) * sizeof(int);
  int* csr_src = (int*)p;       p += (size_t)ET * sizeof(int);

  dim3 b256(256);
  int gGemm = (N_ + 31) / 32;
  int gNode = (N_ + 255) / 256;
  int gEdge = (ET + 255) / 256;
  int gAggr = (N_ + 3) / 4;
  int nb = (N_ + 255) / 256;

  // ---- CSR build (edge_index shared by all 3 layers) ----
  hipMemsetAsync(cnt, 0, (size_t)N_ * sizeof(int), stream);
  count_k<<<gEdge, b256, 0, stream>>>(dstp, cnt, ET);
  block_scan_k<<<nb, b256, 0, stream>>>(cnt, row_ptr, bsum, N_);
  bsum_scan_k<<<1, 512, 0, stream>>>(bsum, nb);
  add_off_k<<<gNode, b256, 0, stream>>>(row_ptr, bsum, N_, ET);
  hipMemcpyAsync(cursor, row_ptr, (size_t)N_ * sizeof(int),
                 hipMemcpyDeviceToDevice, stream);
  fill_k<<<gEdge, b256, 0, stream>>>(srcp, dstp, cursor, csr_src, ET);

  // encode: bufA = x @ enc_w + enc_b
  gemm_k<128, true, 0><<<gGemm, b256, 0, stream>>>(x, encw, encb, nullptr, nullptr,
                                                   nullptr, nullptr, bufA, N_);

  // ---- layer 1 (4 heads x 32) ----
  gemm_k<128, false, 4><<<gGemm, b256, 0, stream>>>(bufA, W1, nullptr, as1, ad1,
                                                    es, ed, bufB, N_);
  aggr_csr_k<4, 32, true><<<gAggr, b256, 0, stream>>>(bufB, es, ed, row_ptr,
                                                      csr_src, b1, bufA, N_);

  // ---- layer 2 (4 heads x 32) ----
  gemm_k<128, false, 4><<<gGemm, b256, 0, stream>>>(bufA, W2, nullptr, as2, ad2,
                                                    es, ed, bufB, N_);
  aggr_csr_k<4, 32, true><<<gAggr, b256, 0, stream>>>(bufB, es, ed, row_ptr,
                                                      csr_src, b2, bufA, N_);

  // ---- layer 3 (1 head x 64) -> d_out ----
  gemm_k<64, false, 1><<<gGemm, b256, 0, stream>>>(bufA, W3, nullptr, as3, ad3,
                                                   es, ed, bufB, N_);
  aggr_csr_k<1, 64, false><<<gAggr, b256, 0, stream>>>(bufB, es, ed, row_ptr,
                                                       csr_src, b3, out, N_);
}

// Round 8
// 872.045 us; speedup vs baseline: 5.6987x; 1.0272x over previous
//
#include <hip/hip_runtime.h>

// GAT via device-built CSR. Encode GEMM folded into layer-1 (W_eff = Ew@W1).
// Aggregation: single-pass no-max segment softmax, one 16-lane group per dst,
// no LDS / no shuffles (den replicated per head-quad), depth-2 pipeline.

// ------- GEMM: Y[n,OUTC] = X[n,128] @ W[128,OUTC] (+bias) (+es/ed epilogue) -------
template <int OUTC, bool BIAS, int NH>
__global__ __launch_bounds__(256) void gemm_k(const float* __restrict__ X,
                                              const float* __restrict__ W,
                                              const float* __restrict__ B,
                                              const float* __restrict__ AS,
                                              const float* __restrict__ AD,
                                              float* __restrict__ es,
                                              float* __restrict__ ed,
                                              float* __restrict__ Y, int n) {
  __shared__ float sW[128 * OUTC];
  __shared__ float sX[32 * 128];
  for (int i = threadIdx.x * 4; i < 128 * OUTC; i += 256 * 4)
    *(float4*)&sW[i] = *(const float4*)&W[i];
  int row0 = blockIdx.x * 32;
  for (int i = threadIdx.x * 4; i < 32 * 128; i += 256 * 4) {
    int r = i >> 7, c = i & 127;
    int gr = row0 + r;
    float4 v = make_float4(0.f, 0.f, 0.f, 0.f);
    if (gr < n) v = *(const float4*)&X[(size_t)gr * 128 + c];
    *(float4*)&sX[i] = v;
  }
  __syncthreads();
  const int tx = threadIdx.x & 31;
  const int ty = threadIdx.x >> 5;
  constexpr int CPT = OUTC / 32;
  const int c0 = tx * CPT;
  const int r0 = ty * 4;
  float acc[4][CPT];
#pragma unroll
  for (int r = 0; r < 4; r++)
#pragma unroll
    for (int c = 0; c < CPT; c++) acc[r][c] = 0.f;

  for (int k = 0; k < 128; k += 4) {
    float4 xv0 = *(float4*)&sX[(r0 + 0) * 128 + k];
    float4 xv1 = *(float4*)&sX[(r0 + 1) * 128 + k];
    float4 xv2 = *(float4*)&sX[(r0 + 2) * 128 + k];
    float4 xv3 = *(float4*)&sX[(r0 + 3) * 128 + k];
#pragma unroll
    for (int kk = 0; kk < 4; kk++) {
      float w[CPT];
#pragma unroll
      for (int c = 0; c < CPT; c++) w[c] = sW[(k + kk) * OUTC + c0 + c];
      float x0 = (&xv0.x)[kk], x1 = (&xv1.x)[kk], x2 = (&xv2.x)[kk], x3 = (&xv3.x)[kk];
#pragma unroll
      for (int c = 0; c < CPT; c++) {
        acc[0][c] = fmaf(x0, w[c], acc[0][c]);
        acc[1][c] = fmaf(x1, w[c], acc[1][c]);
        acc[2][c] = fmaf(x2, w[c], acc[2][c]);
        acc[3][c] = fmaf(x3, w[c], acc[3][c]);
      }
    }
  }
#pragma unroll
  for (int r = 0; r < 4; r++) {
    int gr = row0 + r0 + r;
    if (gr < n) {
#pragma unroll
      for (int c = 0; c < CPT; c++) {
        float v = acc[r][c];
        if (BIAS) v += B[c0 + c];
        Y[(size_t)gr * OUTC + c0 + c] = v;
      }
    }
  }
  // ---- fused attention-coefficient epilogue ----
  if constexpr (NH > 0) {
    constexpr int CH = OUTC / NH;
    constexpr int GRP = CH / CPT;  // lanes per head group (8 or 32)
    float asv[CPT], adv[CPT];
#pragma unroll
    for (int c = 0; c < CPT; c++) { asv[c] = AS[c0 + c]; adv[c] = AD[c0 + c]; }
    float bs = (BIAS) ? 1.f : 1.f;  // (bias already in acc when BIAS)
    (void)bs;
#pragma unroll
    for (int r = 0; r < 4; r++) {
      float ps = 0.f, pd = 0.f;
#pragma unroll
      for (int c = 0; c < CPT; c++) {
        float v = acc[r][c];
        if (BIAS) v += B[c0 + c];
        ps = fmaf(v, asv[c], ps);
        pd = fmaf(v, adv[c], pd);
      }
#pragma unroll
      for (int off = 1; off < GRP; off <<= 1) {
        ps += __shfl_xor(ps, off, 64);
        pd += __shfl_xor(pd, off, 64);
      }
      int gr = row0 + r0 + r;
      if (gr < n && (tx & (GRP - 1)) == 0) {
        int hh = tx / GRP;
        es[(size_t)gr * NH + hh] = ps;
        ed[(size_t)gr * NH + hh] = pd;
      }
    }
  }
}

// ---------------- weight fold: Weff = EW @ W1, beff = EB @ W1 ----------------
__global__ __launch_bounds__(256) void wfold_k(const float* __restrict__ EW,
                                               const float* __restrict__ W1,
                                               const float* __restrict__ EB,
                                               float* __restrict__ Weff,
                                               float* __restrict__ beff) {
  if (blockIdx.x == 16) {
    int c = threadIdx.x;
    if (c < 128) {
      float acc = 0.f;
      for (int k = 0; k < 128; k++) acc = fmaf(EB[k], W1[k * 128 + c], acc);
      beff[c] = acc;
    }
    return;
  }
  int row = blockIdx.x * 8 + (threadIdx.x >> 5);
  int c0 = (threadIdx.x & 31) * 4;
  float4 acc = make_float4(0.f, 0.f, 0.f, 0.f);
  for (int k = 0; k < 128; k++) {
    float xv = EW[row * 128 + k];
    float4 wv = *(const float4*)&W1[k * 128 + c0];
    acc.x = fmaf(xv, wv.x, acc.x);
    acc.y = fmaf(xv, wv.y, acc.y);
    acc.z = fmaf(xv, wv.z, acc.z);
    acc.w = fmaf(xv, wv.w, acc.w);
  }
  *(float4*)&Weff[row * 128 + c0] = acc;
}

// ---------------- CSR build ----------------
__global__ __launch_bounds__(256) void count_k(const int* __restrict__ dst,
                                               int* __restrict__ cnt, int ET) {
  int e = blockIdx.x * 256 + threadIdx.x;
  if (e < ET) atomicAdd(&cnt[dst[e]], 1);
}

__global__ __launch_bounds__(256) void block_scan_k(const int* __restrict__ cnt,
                                                    int* __restrict__ row_ptr,
                                                    int* __restrict__ bsum, int n) {
  __shared__ int s[256];
  int t = threadIdx.x;
  int idx = blockIdx.x * 256 + t;
  int val = (idx < n) ? cnt[idx] : 0;
  s[t] = val;
  __syncthreads();
  for (int off = 1; off < 256; off <<= 1) {
    int x = (t >= off) ? s[t - off] : 0;
    __syncthreads();
    s[t] += x;
    __syncthreads();
  }
  if (idx < n) row_ptr[idx] = s[t] - val;  // exclusive
  if (t == 255) bsum[blockIdx.x] = s[255];
}

// single-block parallel exclusive scan of bsum (nb <= 512)
__global__ __launch_bounds__(512) void bsum_scan_k(int* __restrict__ bsum, int nb) {
  __shared__ int s[512];
  int t = threadIdx.x;
  int v = (t < nb) ? bsum[t] : 0;
  s[t] = v;
  __syncthreads();
  for (int off = 1; off < 512; off <<= 1) {
    int x = (t >= off) ? s[t - off] : 0;
    __syncthreads();
    s[t] += x;
    __syncthreads();
  }
  if (t < nb) bsum[t] = s[t] - v;  // exclusive
}

// adds block offsets AND initializes cursor (replaces d2d memcpy)
__global__ __launch_bounds__(256) void add_off_k(int* __restrict__ row_ptr,
                                                 int* __restrict__ cursor,
                                                 const int* __restrict__ bsum,
                                                 int n, int ET) {
  int idx = blockIdx.x * 256 + threadIdx.x;
  if (idx < n) {
    int v = row_ptr[idx] + bsum[idx >> 8];
    row_ptr[idx] = v;
    cursor[idx] = v;
  }
  if (idx == 0) row_ptr[n] = ET;
}

__global__ __launch_bounds__(256) void fill_k(const int* __restrict__ src,
                                              const int* __restrict__ dst,
                                              int* __restrict__ cursor,
                                              int* __restrict__ csr_src, int ET) {
  int e = blockIdx.x * 256 + threadIdx.x;
  if (e >= ET) return;
  int pos = atomicAdd(&cursor[dst[e]], 1);
  csr_src[pos] = src[e];
}

// -------- fused segment softmax + aggregation: one 16-lane group per dst ------
// No max-subtraction (|es+ed| << 80, exp safe in fp32). No LDS, no shuffles:
// den is accumulated per lane (identical within a head's lane-quad).
template <int NH, int CH, bool RELU>
__global__ __launch_bounds__(256) void aggr_csr_k(const float* __restrict__ H,
                                                  const float* __restrict__ es,
                                                  const float* __restrict__ ed,
                                                  const int* __restrict__ row_ptr,
                                                  const int* __restrict__ csr_src,
                                                  const float* __restrict__ bias,
                                                  float* __restrict__ out, int n) {
  constexpr int NC = NH * CH;   // 128 or 64
  constexpr int CPL = NC / 16;  // channels per lane: 8 or 4
  constexpr int F4 = CPL / 4;   // float4 per lane: 2 or 1

  const int g = threadIdx.x >> 4;
  const int d = blockIdx.x * 16 + g;
  if (d >= n) return;
  const int gl = threadIdx.x & 15;
  const int ch0 = gl * CPL;
  const int head = (NH == 4) ? (ch0 >> 5) : 0;  // CH==32 for NH==4
  const int beg = row_ptr[d];
  const int deg = row_ptr[d + 1] - beg;  // >= 1 (self-loops)
  const float ed_h = ed[(size_t)d * NH + head];

  float den = 0.f;
  float4 a0 = make_float4(0.f, 0.f, 0.f, 0.f);
  float4 a1 = make_float4(0.f, 0.f, 0.f, 0.f);

  // depth-2 pipeline
  int s_c = csr_src[beg];
  float e_c = es[(size_t)s_c * NH + head];
  float4 h0c, h1c;
  {
    const float4* hp = (const float4*)&H[(size_t)s_c * NC + ch0];
    h0c = hp[0];
    if constexpr (F4 == 2) h1c = hp[1];
  }
  for (int i = 0; i < deg; i++) {
    float e_n = 0.f;
    float4 h0n = make_float4(0.f, 0.f, 0.f, 0.f), h1n = h0n;
    if (i + 1 < deg) {
      int s_n = csr_src[beg + i + 1];
      e_n = es[(size_t)s_n * NH + head];
      const float4* hq = (const float4*)&H[(size_t)s_n * NC + ch0];
      h0n = hq[0];
      if constexpr (F4 == 2) h1n = hq[1];
    }
    float vv = e_c + ed_h;
    vv = vv >= 0.f ? vv : 0.2f * vv;  // leaky relu
    float ex = __expf(vv);            // no max-sub: args are O(1)
    den += ex;
    a0.x = fmaf(h0c.x, ex, a0.x);
    a0.y = fmaf(h0c.y, ex, a0.y);
    a0.z = fmaf(h0c.z, ex, a0.z);
    a0.w = fmaf(h0c.w, ex, a0.w);
    if constexpr (F4 == 2) {
      a1.x = fmaf(h1c.x, ex, a1.x);
      a1.y = fmaf(h1c.y, ex, a1.y);
      a1.z = fmaf(h1c.z, ex, a1.z);
      a1.w = fmaf(h1c.w, ex, a1.w);
    }
    e_c = e_n;
    h0c = h0n;
    if constexpr (F4 == 2) h1c = h1n;
  }

  float inv = 1.f / den;
  float4 bv0 = *(const float4*)&bias[ch0];
  float4 o0;
  o0.x = fmaf(a0.x, inv, bv0.x);
  o0.y = fmaf(a0.y, inv, bv0.y);
  o0.z = fmaf(a0.z, inv, bv0.z);
  o0.w = fmaf(a0.w, inv, bv0.w);
  if (RELU) {
    o0.x = fmaxf(o0.x, 0.f); o0.y = fmaxf(o0.y, 0.f);
    o0.z = fmaxf(o0.z, 0.f); o0.w = fmaxf(o0.w, 0.f);
  }
  *(float4*)&out[(size_t)d * NC + ch0] = o0;
  if constexpr (F4 == 2) {
    float4 bv1 = *(const float4*)&bias[ch0 + 4];
    float4 o1;
    o1.x = fmaf(a1.x, inv, bv1.x);
    o1.y = fmaf(a1.y, inv, bv1.y);
    o1.z = fmaf(a1.z, inv, bv1.z);
    o1.w = fmaf(a1.w, inv, bv1.w);
    if (RELU) {
      o1.x = fmaxf(o1.x, 0.f); o1.y = fmaxf(o1.y, 0.f);
      o1.z = fmaxf(o1.z, 0.f); o1.w = fmaxf(o1.w, 0.f);
    }
    *(float4*)&out[(size_t)d * NC + ch0 + 4] = o1;
  }
}

extern "C" void kernel_launch(void* const* d_in, const int* in_sizes, int n_in,
                              void* d_out, int out_size, void* d_ws, size_t ws_size,
                              hipStream_t stream) {
  const float* x = (const float*)d_in[0];
  const float* encw = (const float*)d_in[2];
  const float* encb = (const float*)d_in[3];
  const float* W1 = (const float*)d_in[4];
  const float* as1 = (const float*)d_in[5];
  const float* ad1 = (const float*)d_in[6];
  const float* b1 = (const float*)d_in[7];
  const float* W2 = (const float*)d_in[8];
  const float* as2 = (const float*)d_in[9];
  const float* ad2 = (const float*)d_in[10];
  const float* b2 = (const float*)d_in[11];
  const float* W3 = (const float*)d_in[12];
  const float* as3 = (const float*)d_in[13];
  const float* ad3 = (const float*)d_in[14];
  const float* b3 = (const float*)d_in[15];
  const int* ei = (const int*)d_in[16];

  const int N_ = in_sizes[0] / 128;
  const int ET = in_sizes[16] / 2;
  const int* srcp = ei;
  const int* dstp = ei + ET;
  float* out = (float*)d_out;

  // workspace carve-up
  size_t NB = (size_t)N_ * 128 * sizeof(float);
  char* p = (char*)d_ws;
  float* bufA = (float*)p;      p += NB;
  float* bufB = (float*)p;      p += NB;
  float* es = (float*)p;        p += (size_t)N_ * 4 * sizeof(float);
  float* ed = (float*)p;        p += (size_t)N_ * 4 * sizeof(float);
  int* cnt = (int*)p;           p += (size_t)N_ * sizeof(int);
  int* row_ptr = (int*)p;       p += (size_t)(N_ + 1) * sizeof(int);
  int* cursor = (int*)p;        p += (size_t)N_ * sizeof(int);
  int* bsum = (int*)p;          p += (size_t)((N_ + 255) / 256) * sizeof(int);
  int* csr_src = (int*)p;       p += (size_t)ET * sizeof(int);
  float* Weff = (float*)p;      p += (size_t)128 * 128 * sizeof(float);
  float* beff = (float*)p;      p += (size_t)128 * sizeof(float);

  dim3 b256(256);
  int gGemm = (N_ + 31) / 32;
  int gNode = (N_ + 255) / 256;
  int gEdge = (ET + 255) / 256;
  int gAggr = (N_ + 15) / 16;
  int nb = (N_ + 255) / 256;

  // ---- weight fold (tiny) + CSR build ----
  wfold_k<<<17, b256, 0, stream>>>(encw, W1, encb, Weff, beff);
  hipMemsetAsync(cnt, 0, (size_t)N_ * sizeof(int), stream);
  count_k<<<gEdge, b256, 0, stream>>>(dstp, cnt, ET);
  block_scan_k<<<nb, b256, 0, stream>>>(cnt, row_ptr, bsum, N_);
  bsum_scan_k<<<1, 512, 0, stream>>>(bsum, nb);
  add_off_k<<<gNode, b256, 0, stream>>>(row_ptr, cursor, bsum, N_, ET);
  fill_k<<<gEdge, b256, 0, stream>>>(srcp, dstp, cursor, csr_src, ET);

  // ---- layer 1 (4 heads x 32): H1 = x @ Weff + beff (encode folded) ----
  gemm_k<128, true, 4><<<gGemm, b256, 0, stream>>>(x, Weff, beff, as1, ad1,
                                                   es, ed, bufB, N_);
  aggr_csr_k<4, 32, true><<<gAggr, b256, 0, stream>>>(bufB, es, ed, row_ptr,
                                                      csr_src, b1, bufA, N_);

  // ---- layer 2 (4 heads x 32) ----
  gemm_k<128, false, 4><<<gGemm, b256, 0, stream>>>(bufA, W2, nullptr, as2, ad2,
                                                    es, ed, bufB, N_);
  aggr_csr_k<4, 32, true><<<gAggr, b256, 0, stream>>>(bufB, es, ed, row_ptr,
                                                      csr_src, b2, bufA, N_);

  // ---- layer 3 (1 head x 64) -> d_out ----
  gemm_k<64, false, 1><<<gGemm, b256, 0, stream>>>(bufA, W3, nullptr, as3, ad3,
                                                   es, ed, bufB, N_);
  aggr_csr_k<1, 64, false><<<gAggr, b256, 0, stream>>>(bufB, es, ed, row_ptr,
                                                       csr_src, b3, out, N_);
}

// Round 9
// 756.330 us; speedup vs baseline: 6.5706x; 1.1530x over previous
//
#include <hip/hip_runtime.h>
#include <hip/hip_fp16.h>

// GAT via device-built CSR. Encode GEMM folded into layer-1 (W_eff = Ew@W1).
// Layers 1/2: GEMM writes H as fp16 ONLY (gather halves its traffic); es/ed
// from fp32 accs in GEMM epilogue. Layer 3 H stays fp32 (feeds output).
// Aggregation: single-pass no-max softmax, one 16-lane group per dst.

// ------- GEMM: (+bias) (+es/ed epilogue) (+fp16 or fp32 H output) -------
template <int OUTC, bool BIAS, int NH, bool HOUT>
__global__ __launch_bounds__(256) void gemm_k(const float* __restrict__ X,
                                              const float* __restrict__ W,
                                              const float* __restrict__ B,
                                              const float* __restrict__ AS,
                                              const float* __restrict__ AD,
                                              float* __restrict__ es,
                                              float* __restrict__ ed,
                                              float* __restrict__ Y,
                                              __half* __restrict__ Hh, int n) {
  __shared__ float sW[128 * OUTC];
  __shared__ float sX[32 * 128];
  for (int i = threadIdx.x * 4; i < 128 * OUTC; i += 256 * 4)
    *(float4*)&sW[i] = *(const float4*)&W[i];
  int row0 = blockIdx.x * 32;
  for (int i = threadIdx.x * 4; i < 32 * 128; i += 256 * 4) {
    int r = i >> 7, c = i & 127;
    int gr = row0 + r;
    float4 v = make_float4(0.f, 0.f, 0.f, 0.f);
    if (gr < n) v = *(const float4*)&X[(size_t)gr * 128 + c];
    *(float4*)&sX[i] = v;
  }
  __syncthreads();
  const int tx = threadIdx.x & 31;
  const int ty = threadIdx.x >> 5;
  constexpr int CPT = OUTC / 32;
  const int c0 = tx * CPT;
  const int r0 = ty * 4;
  float acc[4][CPT];
#pragma unroll
  for (int r = 0; r < 4; r++)
#pragma unroll
    for (int c = 0; c < CPT; c++) acc[r][c] = 0.f;

  for (int k = 0; k < 128; k += 4) {
    float4 xv0 = *(float4*)&sX[(r0 + 0) * 128 + k];
    float4 xv1 = *(float4*)&sX[(r0 + 1) * 128 + k];
    float4 xv2 = *(float4*)&sX[(r0 + 2) * 128 + k];
    float4 xv3 = *(float4*)&sX[(r0 + 3) * 128 + k];
#pragma unroll
    for (int kk = 0; kk < 4; kk++) {
      float w[CPT];
#pragma unroll
      for (int c = 0; c < CPT; c++) w[c] = sW[(k + kk) * OUTC + c0 + c];
      float x0 = (&xv0.x)[kk], x1 = (&xv1.x)[kk], x2 = (&xv2.x)[kk], x3 = (&xv3.x)[kk];
#pragma unroll
      for (int c = 0; c < CPT; c++) {
        acc[0][c] = fmaf(x0, w[c], acc[0][c]);
        acc[1][c] = fmaf(x1, w[c], acc[1][c]);
        acc[2][c] = fmaf(x2, w[c], acc[2][c]);
        acc[3][c] = fmaf(x3, w[c], acc[3][c]);
      }
    }
  }
  // fold bias into acc once
  if constexpr (BIAS) {
#pragma unroll
    for (int r = 0; r < 4; r++)
#pragma unroll
      for (int c = 0; c < CPT; c++) acc[r][c] += B[c0 + c];
  }
#pragma unroll
  for (int r = 0; r < 4; r++) {
    int gr = row0 + r0 + r;
    if (gr < n) {
      if constexpr (HOUT) {
        // OUTC==128, CPT==4: pack 4 halves (8B)
        __half2 p0 = __floats2half2_rn(acc[r][0], acc[r][1]);
        __half2 p1 = __floats2half2_rn(acc[r][2], acc[r][3]);
        uint2 pk;
        pk.x = *reinterpret_cast<unsigned*>(&p0);
        pk.y = *reinterpret_cast<unsigned*>(&p1);
        *(uint2*)&Hh[(size_t)gr * OUTC + c0] = pk;
      } else {
#pragma unroll
        for (int c = 0; c < CPT; c++)
          Y[(size_t)gr * OUTC + c0 + c] = acc[r][c];
      }
    }
  }
  // ---- fused attention-coefficient epilogue (from fp32 accs) ----
  if constexpr (NH > 0) {
    constexpr int CH = OUTC / NH;
    constexpr int GRP = CH / CPT;  // lanes per head group (8 or 32)
    float asv[CPT], adv[CPT];
#pragma unroll
    for (int c = 0; c < CPT; c++) { asv[c] = AS[c0 + c]; adv[c] = AD[c0 + c]; }
#pragma unroll
    for (int r = 0; r < 4; r++) {
      float ps = 0.f, pd = 0.f;
#pragma unroll
      for (int c = 0; c < CPT; c++) {
        ps = fmaf(acc[r][c], asv[c], ps);
        pd = fmaf(acc[r][c], adv[c], pd);
      }
#pragma unroll
      for (int off = 1; off < GRP; off <<= 1) {
        ps += __shfl_xor(ps, off, 64);
        pd += __shfl_xor(pd, off, 64);
      }
      int gr = row0 + r0 + r;
      if (gr < n && (tx & (GRP - 1)) == 0) {
        int hh = tx / GRP;
        es[(size_t)gr * NH + hh] = ps;
        ed[(size_t)gr * NH + hh] = pd;
      }
    }
  }
}

// ---------------- weight fold: Weff = EW @ W1, beff = EB @ W1 ----------------
__global__ __launch_bounds__(256) void wfold_k(const float* __restrict__ EW,
                                               const float* __restrict__ W1,
                                               const float* __restrict__ EB,
                                               float* __restrict__ Weff,
                                               float* __restrict__ beff) {
  if (blockIdx.x == 16) {
    int c = threadIdx.x;
    if (c < 128) {
      float acc = 0.f;
      for (int k = 0; k < 128; k++) acc = fmaf(EB[k], W1[k * 128 + c], acc);
      beff[c] = acc;
    }
    return;
  }
  int row = blockIdx.x * 8 + (threadIdx.x >> 5);
  int c0 = (threadIdx.x & 31) * 4;
  float4 acc = make_float4(0.f, 0.f, 0.f, 0.f);
  for (int k = 0; k < 128; k++) {
    float xv = EW[row * 128 + k];
    float4 wv = *(const float4*)&W1[k * 128 + c0];
    acc.x = fmaf(xv, wv.x, acc.x);
    acc.y = fmaf(xv, wv.y, acc.y);
    acc.z = fmaf(xv, wv.z, acc.z);
    acc.w = fmaf(xv, wv.w, acc.w);
  }
  *(float4*)&Weff[row * 128 + c0] = acc;
}

// ---------------- CSR build ----------------
__global__ __launch_bounds__(256) void count_k(const int* __restrict__ dst,
                                               int* __restrict__ cnt, int ET) {
  int e = blockIdx.x * 256 + threadIdx.x;
  if (e < ET) atomicAdd(&cnt[dst[e]], 1);
}

__global__ __launch_bounds__(256) void block_scan_k(const int* __restrict__ cnt,
                                                    int* __restrict__ row_ptr,
                                                    int* __restrict__ bsum, int n) {
  __shared__ int s[256];
  int t = threadIdx.x;
  int idx = blockIdx.x * 256 + t;
  int val = (idx < n) ? cnt[idx] : 0;
  s[t] = val;
  __syncthreads();
  for (int off = 1; off < 256; off <<= 1) {
    int x = (t >= off) ? s[t - off] : 0;
    __syncthreads();
    s[t] += x;
    __syncthreads();
  }
  if (idx < n) row_ptr[idx] = s[t] - val;  // exclusive
  if (t == 255) bsum[blockIdx.x] = s[255];
}

__global__ __launch_bounds__(512) void bsum_scan_k(int* __restrict__ bsum, int nb) {
  __shared__ int s[512];
  int t = threadIdx.x;
  int v = (t < nb) ? bsum[t] : 0;
  s[t] = v;
  __syncthreads();
  for (int off = 1; off < 512; off <<= 1) {
    int x = (t >= off) ? s[t - off] : 0;
    __syncthreads();
    s[t] += x;
    __syncthreads();
  }
  if (t < nb) bsum[t] = s[t] - v;  // exclusive
}

__global__ __launch_bounds__(256) void add_off_k(int* __restrict__ row_ptr,
                                                 int* __restrict__ cursor,
                                                 const int* __restrict__ bsum,
                                                 int n, int ET) {
  int idx = blockIdx.x * 256 + threadIdx.x;
  if (idx < n) {
    int v = row_ptr[idx] + bsum[idx >> 8];
    row_ptr[idx] = v;
    cursor[idx] = v;
  }
  if (idx == 0) row_ptr[n] = ET;
}

__global__ __launch_bounds__(256) void fill_k(const int* __restrict__ src,
                                              const int* __restrict__ dst,
                                              int* __restrict__ cursor,
                                              int* __restrict__ csr_src, int ET) {
  int e = blockIdx.x * 256 + threadIdx.x;
  if (e >= ET) return;
  int pos = atomicAdd(&cursor[dst[e]], 1);
  csr_src[pos] = src[e];
}

// -------- fused segment softmax + aggregation: one 16-lane group per dst ------
// HALF: gather H in fp16 (uint4 = 8 halves/lane). !HALF: fp32 float4 (CPL=4).
template <int NH, int CH, bool RELU, bool HALF>
__global__ __launch_bounds__(256) void aggr_csr_k(const float* __restrict__ Hf,
                                                  const __half* __restrict__ Hh,
                                                  const float* __restrict__ es,
                                                  const float* __restrict__ ed,
                                                  const int* __restrict__ row_ptr,
                                                  const int* __restrict__ csr_src,
                                                  const float* __restrict__ bias,
                                                  float* __restrict__ out, int n) {
  constexpr int NC = NH * CH;   // 128 or 64
  constexpr int CPL = NC / 16;  // channels per lane: 8 (HALF) or 4 (fp32)
  static_assert((HALF && CPL == 8) || (!HALF && CPL == 4), "layout");

  const int g = threadIdx.x >> 4;
  const int d = blockIdx.x * 16 + g;
  if (d >= n) return;
  const int gl = threadIdx.x & 15;
  const int ch0 = gl * CPL;
  const int head = (NH == 4) ? (ch0 >> 5) : 0;
  const int beg = row_ptr[d];
  const int deg = row_ptr[d + 1] - beg;  // >= 1 (self-loops)
  const float ed_h = ed[(size_t)d * NH + head];

  float den = 0.f;
  float a[CPL];
#pragma unroll
  for (int c = 0; c < CPL; c++) a[c] = 0.f;

  // depth-2 pipeline
  int s_c = csr_src[beg];
  float e_c = es[(size_t)s_c * NH + head];
  uint4 hr_c = make_uint4(0, 0, 0, 0);
  float4 hf_c = make_float4(0.f, 0.f, 0.f, 0.f);
  if constexpr (HALF) hr_c = *(const uint4*)&Hh[(size_t)s_c * NC + ch0];
  else hf_c = *(const float4*)&Hf[(size_t)s_c * NC + ch0];

  for (int i = 0; i < deg; i++) {
    float e_n = 0.f;
    uint4 hr_n = make_uint4(0, 0, 0, 0);
    float4 hf_n = make_float4(0.f, 0.f, 0.f, 0.f);
    if (i + 1 < deg) {
      int s_n = csr_src[beg + i + 1];
      e_n = es[(size_t)s_n * NH + head];
      if constexpr (HALF) hr_n = *(const uint4*)&Hh[(size_t)s_n * NC + ch0];
      else hf_n = *(const float4*)&Hf[(size_t)s_n * NC + ch0];
    }
    float vv = e_c + ed_h;
    vv = vv >= 0.f ? vv : 0.2f * vv;  // leaky relu
    float ex = __expf(vv);            // no max-sub: args are O(1)
    den += ex;
    if constexpr (HALF) {
      const unsigned* u = &hr_c.x;
#pragma unroll
      for (int q = 0; q < 4; q++) {
        __half2 h2 = *reinterpret_cast<const __half2*>(&u[q]);
        float2 f2 = __half22float2(h2);
        a[2 * q]     = fmaf(f2.x, ex, a[2 * q]);
        a[2 * q + 1] = fmaf(f2.y, ex, a[2 * q + 1]);
      }
    } else {
      a[0] = fmaf(hf_c.x, ex, a[0]);
      a[1] = fmaf(hf_c.y, ex, a[1]);
      a[2] = fmaf(hf_c.z, ex, a[2]);
      a[3] = fmaf(hf_c.w, ex, a[3]);
    }
    e_c = e_n;
    hr_c = hr_n;
    hf_c = hf_n;
  }

  float inv = 1.f / den;
#pragma unroll
  for (int q = 0; q < CPL / 4; q++) {
    float4 bv = *(const float4*)&bias[ch0 + 4 * q];
    float4 o;
    o.x = fmaf(a[4 * q + 0], inv, bv.x);
    o.y = fmaf(a[4 * q + 1], inv, bv.y);
    o.z = fmaf(a[4 * q + 2], inv, bv.z);
    o.w = fmaf(a[4 * q + 3], inv, bv.w);
    if (RELU) {
      o.x = fmaxf(o.x, 0.f); o.y = fmaxf(o.y, 0.f);
      o.z = fmaxf(o.z, 0.f); o.w = fmaxf(o.w, 0.f);
    }
    *(float4*)&out[(size_t)d * NC + ch0 + 4 * q] = o;
  }
}

extern "C" void kernel_launch(void* const* d_in, const int* in_sizes, int n_in,
                              void* d_out, int out_size, void* d_ws, size_t ws_size,
                              hipStream_t stream) {
  const float* x = (const float*)d_in[0];
  const float* encw = (const float*)d_in[2];
  const float* encb = (const float*)d_in[3];
  const float* W1 = (const float*)d_in[4];
  const float* as1 = (const float*)d_in[5];
  const float* ad1 = (const float*)d_in[6];
  const float* b1 = (const float*)d_in[7];
  const float* W2 = (const float*)d_in[8];
  const float* as2 = (const float*)d_in[9];
  const float* ad2 = (const float*)d_in[10];
  const float* b2 = (const float*)d_in[11];
  const float* W3 = (const float*)d_in[12];
  const float* as3 = (const float*)d_in[13];
  const float* ad3 = (const float*)d_in[14];
  const float* b3 = (const float*)d_in[15];
  const int* ei = (const int*)d_in[16];

  const int N_ = in_sizes[0] / 128;
  const int ET = in_sizes[16] / 2;
  const int* srcp = ei;
  const int* dstp = ei + ET;
  float* out = (float*)d_out;

  // workspace carve-up (Hh shares bufB's slot: 25.6 MB < 51.2 MB)
  size_t NB = (size_t)N_ * 128 * sizeof(float);
  char* p = (char*)d_ws;
  float* bufA = (float*)p;      p += NB;
  float* bufB = (float*)p;      p += NB;
  __half* Hh = (__half*)bufB;   // fp16 H for layers 1/2 (aliases bufB)
  float* es = (float*)p;        p += (size_t)N_ * 4 * sizeof(float);
  float* ed = (float*)p;        p += (size_t)N_ * 4 * sizeof(float);
  int* cnt = (int*)p;           p += (size_t)N_ * sizeof(int);
  int* row_ptr = (int*)p;       p += (size_t)(N_ + 1) * sizeof(int);
  int* cursor = (int*)p;        p += (size_t)N_ * sizeof(int);
  int* bsum = (int*)p;          p += (size_t)((N_ + 255) / 256) * sizeof(int);
  int* csr_src = (int*)p;       p += (size_t)ET * sizeof(int);
  float* Weff = (float*)p;      p += (size_t)128 * 128 * sizeof(float);
  float* beff = (float*)p;      p += (size_t)128 * sizeof(float);

  dim3 b256(256);
  int gGemm = (N_ + 31) / 32;
  int gNode = (N_ + 255) / 256;
  int gEdge = (ET + 255) / 256;
  int gAggr = (N_ + 15) / 16;
  int nb = (N_ + 255) / 256;

  // ---- weight fold (tiny) + CSR build ----
  wfold_k<<<17, b256, 0, stream>>>(encw, W1, encb, Weff, beff);
  hipMemsetAsync(cnt, 0, (size_t)N_ * sizeof(int), stream);
  count_k<<<gEdge, b256, 0, stream>>>(dstp, cnt, ET);
  block_scan_k<<<nb, b256, 0, stream>>>(cnt, row_ptr, bsum, N_);
  bsum_scan_k<<<1, 512, 0, stream>>>(bsum, nb);
  add_off_k<<<gNode, b256, 0, stream>>>(row_ptr, cursor, bsum, N_, ET);
  fill_k<<<gEdge, b256, 0, stream>>>(srcp, dstp, cursor, csr_src, ET);

  // ---- layer 1 (4 heads x 32): H1(fp16) = x @ Weff + beff (encode folded) ----
  gemm_k<128, true, 4, true><<<gGemm, b256, 0, stream>>>(x, Weff, beff, as1, ad1,
                                                         es, ed, nullptr, Hh, N_);
  aggr_csr_k<4, 32, true, true><<<gAggr, b256, 0, stream>>>(nullptr, Hh, es, ed,
                                                            row_ptr, csr_src, b1,
                                                            bufA, N_);

  // ---- layer 2 (4 heads x 32): H2 in fp16 ----
  gemm_k<128, false, 4, true><<<gGemm, b256, 0, stream>>>(bufA, W2, nullptr, as2, ad2,
                                                          es, ed, nullptr, Hh, N_);
  aggr_csr_k<4, 32, true, true><<<gAggr, b256, 0, stream>>>(nullptr, Hh, es, ed,
                                                            row_ptr, csr_src, b2,
                                                            bufA, N_);

  // ---- layer 3 (1 head x 64): H3 fp32 (feeds output directly) ----
  gemm_k<64, false, 1, false><<<gGemm, b256, 0, stream>>>(bufA, W3, nullptr, as3, ad3,
                                                          es, ed, bufB, nullptr, N_);
  aggr_csr_k<1, 64, false, false><<<gAggr, b256, 0, stream>>>(bufB, nullptr, es, ed,
                                                              row_ptr, csr_src, b3,
                                                              out, N_);
}

// Round 11
// 670.950 us; speedup vs baseline: 7.4068x; 1.1273x over previous
//
#include <hip/hip_runtime.h>
#include <hip/hip_fp16.h>

// GAT via device-built CSR. Encode GEMM folded into layer-1 (W_eff = Ew@W1).
// Layers 1/2: GEMM writes H as fp16 ONLY; es/ed from fp32 accs in epilogue.
// CSR: rank-based counting sort — one returning-atomic pass (coalesced rank
// store), then an atomic-free scatter fill.
// Aggregation: single-pass no-max softmax, one 16-lane group per dst.

// ------- GEMM: (+bias) (+es/ed epilogue) (+fp16 or fp32 H output) -------
template <int OUTC, bool BIAS, int NH, bool HOUT>
__global__ __launch_bounds__(256) void gemm_k(const float* __restrict__ X,
                                              const float* __restrict__ W,
                                              const float* __restrict__ B,
                                              const float* __restrict__ AS,
                                              const float* __restrict__ AD,
                                              float* __restrict__ es,
                                              float* __restrict__ ed,
                                              float* __restrict__ Y,
                                              __half* __restrict__ Hh, int n) {
  __shared__ float sW[128 * OUTC];
  __shared__ float sX[32 * 128];
  for (int i = threadIdx.x * 4; i < 128 * OUTC; i += 256 * 4)
    *(float4*)&sW[i] = *(const float4*)&W[i];
  int row0 = blockIdx.x * 32;
  for (int i = threadIdx.x * 4; i < 32 * 128; i += 256 * 4) {
    int r = i >> 7, c = i & 127;
    int gr = row0 + r;
    float4 v = make_float4(0.f, 0.f, 0.f, 0.f);
    if (gr < n) v = *(const float4*)&X[(size_t)gr * 128 + c];
    *(float4*)&sX[i] = v;
  }
  __syncthreads();
  const int tx = threadIdx.x & 31;
  const int ty = threadIdx.x >> 5;
  constexpr int CPT = OUTC / 32;
  const int c0 = tx * CPT;
  const int r0 = ty * 4;
  float acc[4][CPT];
#pragma unroll
  for (int r = 0; r < 4; r++)
#pragma unroll
    for (int c = 0; c < CPT; c++) acc[r][c] = 0.f;

  for (int k = 0; k < 128; k += 4) {
    float4 xv0 = *(float4*)&sX[(r0 + 0) * 128 + k];
    float4 xv1 = *(float4*)&sX[(r0 + 1) * 128 + k];
    float4 xv2 = *(float4*)&sX[(r0 + 2) * 128 + k];
    float4 xv3 = *(float4*)&sX[(r0 + 3) * 128 + k];
#pragma unroll
    for (int kk = 0; kk < 4; kk++) {
      float w[CPT];
#pragma unroll
      for (int c = 0; c < CPT; c++) w[c] = sW[(k + kk) * OUTC + c0 + c];
      float x0 = (&xv0.x)[kk], x1 = (&xv1.x)[kk], x2 = (&xv2.x)[kk], x3 = (&xv3.x)[kk];
#pragma unroll
      for (int c = 0; c < CPT; c++) {
        acc[0][c] = fmaf(x0, w[c], acc[0][c]);
        acc[1][c] = fmaf(x1, w[c], acc[1][c]);
        acc[2][c] = fmaf(x2, w[c], acc[2][c]);
        acc[3][c] = fmaf(x3, w[c], acc[3][c]);
      }
    }
  }
  // fold bias into acc once
  if constexpr (BIAS) {
#pragma unroll
    for (int r = 0; r < 4; r++)
#pragma unroll
      for (int c = 0; c < CPT; c++) acc[r][c] += B[c0 + c];
  }
#pragma unroll
  for (int r = 0; r < 4; r++) {
    int gr = row0 + r0 + r;
    if (gr < n) {
      if constexpr (HOUT) {
        // OUTC==128, CPT==4: pack 4 halves (8B)
        __half2 p0 = __floats2half2_rn(acc[r][0], acc[r][1]);
        __half2 p1 = __floats2half2_rn(acc[r][2], acc[r][3]);
        uint2 pk;
        pk.x = *reinterpret_cast<unsigned*>(&p0);
        pk.y = *reinterpret_cast<unsigned*>(&p1);
        *(uint2*)&Hh[(size_t)gr * OUTC + c0] = pk;
      } else {
#pragma unroll
        for (int c = 0; c < CPT; c++)
          Y[(size_t)gr * OUTC + c0 + c] = acc[r][c];
      }
    }
  }
  // ---- fused attention-coefficient epilogue (from fp32 accs) ----
  if constexpr (NH > 0) {
    constexpr int CH = OUTC / NH;
    constexpr int GRP = CH / CPT;  // lanes per head group (8 or 32)
    float asv[CPT], adv[CPT];
#pragma unroll
    for (int c = 0; c < CPT; c++) { asv[c] = AS[c0 + c]; adv[c] = AD[c0 + c]; }
#pragma unroll
    for (int r = 0; r < 4; r++) {
      float ps = 0.f, pd = 0.f;
#pragma unroll
      for (int c = 0; c < CPT; c++) {
        ps = fmaf(acc[r][c], asv[c], ps);
        pd = fmaf(acc[r][c], adv[c], pd);
      }
#pragma unroll
      for (int off = 1; off < GRP; off <<= 1) {
        ps += __shfl_xor(ps, off, 64);
        pd += __shfl_xor(pd, off, 64);
      }
      int gr = row0 + r0 + r;
      if (gr < n && (tx & (GRP - 1)) == 0) {
        int hh = tx / GRP;
        es[(size_t)gr * NH + hh] = ps;
        ed[(size_t)gr * NH + hh] = pd;
      }
    }
  }
}

// ---------------- weight fold: Weff = EW @ W1, beff = EB @ W1 ----------------
__global__ __launch_bounds__(256) void wfold_k(const float* __restrict__ EW,
                                               const float* __restrict__ W1,
                                               const float* __restrict__ EB,
                                               float* __restrict__ Weff,
                                               float* __restrict__ beff) {
  if (blockIdx.x == 16) {
    int c = threadIdx.x;
    if (c < 128) {
      float acc = 0.f;
      for (int k = 0; k < 128; k++) acc = fmaf(EB[k], W1[k * 128 + c], acc);
      beff[c] = acc;
    }
    return;
  }
  int row = blockIdx.x * 8 + (threadIdx.x >> 5);
  int c0 = (threadIdx.x & 31) * 4;
  float4 acc = make_float4(0.f, 0.f, 0.f, 0.f);
  for (int k = 0; k < 128; k++) {
    float xv = EW[row * 128 + k];
    float4 wv = *(const float4*)&W1[k * 128 + c0];
    acc.x = fmaf(xv, wv.x, acc.x);
    acc.y = fmaf(xv, wv.y, acc.y);
    acc.z = fmaf(xv, wv.z, acc.z);
    acc.w = fmaf(xv, wv.w, acc.w);
  }
  *(float4*)&Weff[row * 128 + c0] = acc;
}

// ---------------- CSR build (rank-based counting sort) ----------------
// pass 1: rank[e] = atomicAdd(cnt[dst[e]], 1)  (rank store is coalesced,
// fire-and-forget; also produces counts)
__global__ __launch_bounds__(256) void rank_k(const int* __restrict__ dst,
                                              int* __restrict__ cnt,
                                              int* __restrict__ rank, int ET) {
  int e = blockIdx.x * 256 + threadIdx.x;
  if (e < ET) rank[e] = atomicAdd(&cnt[dst[e]], 1);
}

__global__ __launch_bounds__(256) void block_scan_k(const int* __restrict__ cnt,
                                                    int* __restrict__ row_ptr,
                                                    int* __restrict__ bsum, int n) {
  __shared__ int s[256];
  int t = threadIdx.x;
  int idx = blockIdx.x * 256 + t;
  int val = (idx < n) ? cnt[idx] : 0;
  s[t] = val;
  __syncthreads();
  for (int off = 1; off < 256; off <<= 1) {
    int x = (t >= off) ? s[t - off] : 0;
    __syncthreads();
    s[t] += x;
    __syncthreads();
  }
  if (idx < n) row_ptr[idx] = s[t] - val;  // exclusive
  if (t == 255) bsum[blockIdx.x] = s[255];
}

__global__ __launch_bounds__(512) void bsum_scan_k(int* __restrict__ bsum, int nb) {
  __shared__ int s[512];
  int t = threadIdx.x;
  int v = (t < nb) ? bsum[t] : 0;
  s[t] = v;
  __syncthreads();
  for (int off = 1; off < 512; off <<= 1) {
    int x = (t >= off) ? s[t - off] : 0;
    __syncthreads();
    s[t] += x;
    __syncthreads();
  }
  if (t < nb) bsum[t] = s[t] - v;  // exclusive
}

__global__ __launch_bounds__(256) void add_off_k(int* __restrict__ row_ptr,
                                                 const int* __restrict__ bsum,
                                                 int n, int ET) {
  int idx = blockIdx.x * 256 + threadIdx.x;
  if (idx < n) row_ptr[idx] += bsum[idx >> 8];
  if (idx == 0) row_ptr[n] = ET;
}

// pass 2: atomic-free scatter fill
__global__ __launch_bounds__(256) void fill_k(const int* __restrict__ src,
                                              const int* __restrict__ dst,
                                              const int* __restrict__ row_ptr,
                                              const int* __restrict__ rank,
                                              int* __restrict__ csr_src, int ET) {
  int e = blockIdx.x * 256 + threadIdx.x;
  if (e >= ET) return;
  csr_src[row_ptr[dst[e]] + rank[e]] = src[e];
}

// -------- fused segment softmax + aggregation: one 16-lane group per dst ------
// HALF: gather H in fp16 (uint4 = 8 halves/lane). !HALF: fp32 float4 (CPL=4).
template <int NH, int CH, bool RELU, bool HALF>
__global__ __launch_bounds__(256) void aggr_csr_k(const float* __restrict__ Hf,
                                                  const __half* __restrict__ Hh,
                                                  const float* __restrict__ es,
                                                  const float* __restrict__ ed,
                                                  const int* __restrict__ row_ptr,
                                                  const int* __restrict__ csr_src,
                                                  const float* __restrict__ bias,
                                                  float* __restrict__ out, int n) {
  constexpr int NC = NH * CH;   // 128 or 64
  constexpr int CPL = NC / 16;  // channels per lane: 8 (HALF) or 4 (fp32)
  static_assert((HALF && CPL == 8) || (!HALF && CPL == 4), "layout");

  const int g = threadIdx.x >> 4;
  const int d = blockIdx.x * 16 + g;
  if (d >= n) return;
  const int gl = threadIdx.x & 15;
  const int ch0 = gl * CPL;
  const int head = (NH == 4) ? (ch0 >> 5) : 0;
  const int beg = row_ptr[d];
  const int deg = row_ptr[d + 1] - beg;  // >= 1 (self-loops)
  const float ed_h = ed[(size_t)d * NH + head];

  float den = 0.f;
  float a[CPL];
#pragma unroll
  for (int c = 0; c < CPL; c++) a[c] = 0.f;

  // depth-2 pipeline
  int s_c = csr_src[beg];
  float e_c = es[(size_t)s_c * NH + head];
  uint4 hr_c = make_uint4(0, 0, 0, 0);
  float4 hf_c = make_float4(0.f, 0.f, 0.f, 0.f);
  if constexpr (HALF) hr_c = *(const uint4*)&Hh[(size_t)s_c * NC + ch0];
  else hf_c = *(const float4*)&Hf[(size_t)s_c * NC + ch0];

  for (int i = 0; i < deg; i++) {
    float e_n = 0.f;
    uint4 hr_n = make_uint4(0, 0, 0, 0);
    float4 hf_n = make_float4(0.f, 0.f, 0.f, 0.f);
    if (i + 1 < deg) {
      int s_n = csr_src[beg + i + 1];
      e_n = es[(size_t)s_n * NH + head];
      if constexpr (HALF) hr_n = *(const uint4*)&Hh[(size_t)s_n * NC + ch0];
      else hf_n = *(const float4*)&Hf[(size_t)s_n * NC + ch0];
    }
    float vv = e_c + ed_h;
    vv = vv >= 0.f ? vv : 0.2f * vv;  // leaky relu
    float ex = __expf(vv);            // no max-sub: args are O(1)
    den += ex;
    if constexpr (HALF) {
      const unsigned* u = &hr_c.x;
#pragma unroll
      for (int q = 0; q < 4; q++) {
        __half2 h2 = *reinterpret_cast<const __half2*>(&u[q]);
        float2 f2 = __half22float2(h2);
        a[2 * q]     = fmaf(f2.x, ex, a[2 * q]);
        a[2 * q + 1] = fmaf(f2.y, ex, a[2 * q + 1]);
      }
    } else {
      a[0] = fmaf(hf_c.x, ex, a[0]);
      a[1] = fmaf(hf_c.y, ex, a[1]);
      a[2] = fmaf(hf_c.z, ex, a[2]);
      a[3] = fmaf(hf_c.w, ex, a[3]);
    }
    e_c = e_n;
    hr_c = hr_n;
    hf_c = hf_n;
  }

  float inv = 1.f / den;
#pragma unroll
  for (int q = 0; q < CPL / 4; q++) {
    float4 bv = *(const float4*)&bias[ch0 + 4 * q];
    float4 o;
    o.x = fmaf(a[4 * q + 0], inv, bv.x);
    o.y = fmaf(a[4 * q + 1], inv, bv.y);
    o.z = fmaf(a[4 * q + 2], inv, bv.z);
    o.w = fmaf(a[4 * q + 3], inv, bv.w);
    if (RELU) {
      o.x = fmaxf(o.x, 0.f); o.y = fmaxf(o.y, 0.f);
      o.z = fmaxf(o.z, 0.f); o.w = fmaxf(o.w, 0.f);
    }
    *(float4*)&out[(size_t)d * NC + ch0 + 4 * q] = o;
  }
}

extern "C" void kernel_launch(void* const* d_in, const int* in_sizes, int n_in,
                              void* d_out, int out_size, void* d_ws, size_t ws_size,
                              hipStream_t stream) {
  const float* x = (const float*)d_in[0];
  const float* encw = (const float*)d_in[2];
  const float* encb = (const float*)d_in[3];
  const float* W1 = (const float*)d_in[4];
  const float* as1 = (const float*)d_in[5];
  const float* ad1 = (const float*)d_in[6];
  const float* b1 = (const float*)d_in[7];
  const float* W2 = (const float*)d_in[8];
  const float* as2 = (const float*)d_in[9];
  const float* ad2 = (const float*)d_in[10];
  const float* b2 = (const float*)d_in[11];
  const float* W3 = (const float*)d_in[12];
  const float* as3 = (const float*)d_in[13];
  const float* ad3 = (const float*)d_in[14];
  const float* b3 = (const float*)d_in[15];
  const int* ei = (const int*)d_in[16];

  const int N_ = in_sizes[0] / 128;
  const int ET = in_sizes[16] / 2;
  const int* srcp = ei;
  const int* dstp = ei + ET;
  float* out = (float*)d_out;

  // workspace carve-up (Hh aliases bufB; rank aliases bufB too — rank is dead
  // before GEMM1 writes Hh, single stream so no hazard)
  size_t NB = (size_t)N_ * 128 * sizeof(float);
  char* p = (char*)d_ws;
  float* bufA = (float*)p;      p += NB;
  float* bufB = (float*)p;      p += NB;
  __half* Hh = (__half*)bufB;   // fp16 H for layers 1/2
  int* rank = (int*)bufB;       // per-edge rank during CSR build (ET ints)
  float* es = (float*)p;        p += (size_t)N_ * 4 * sizeof(float);
  float* ed = (float*)p;        p += (size_t)N_ * 4 * sizeof(float);
  int* cnt = (int*)p;           p += (size_t)N_ * sizeof(int);
  int* row_ptr = (int*)p;       p += (size_t)(N_ + 1) * sizeof(int);
  int* bsum = (int*)p;          p += (size_t)((N_ + 255) / 256) * sizeof(int);
  int* csr_src = (int*)p;       p += (size_t)ET * sizeof(int);
  float* Weff = (float*)p;      p += (size_t)128 * 128 * sizeof(float);
  float* beff = (float*)p;      p += (size_t)128 * sizeof(float);

  dim3 b256(256);
  int gGemm = (N_ + 31) / 32;
  int gNode = (N_ + 255) / 256;
  int gEdge = (ET + 255) / 256;
  int gAggr = (N_ + 15) / 16;
  int nb = (N_ + 255) / 256;

  // ---- weight fold (tiny) + CSR build ----
  wfold_k<<<17, b256, 0, stream>>>(encw, W1, encb, Weff, beff);
  hipMemsetAsync(cnt, 0, (size_t)N_ * sizeof(int), stream);
  rank_k<<<gEdge, b256, 0, stream>>>(dstp, cnt, rank, ET);
  block_scan_k<<<nb, b256, 0, stream>>>(cnt, row_ptr, bsum, N_);
  bsum_scan_k<<<1, 512, 0, stream>>>(bsum, nb);
  add_off_k<<<gNode, b256, 0, stream>>>(row_ptr, bsum, N_, ET);
  fill_k<<<gEdge, b256, 0, stream>>>(srcp, dstp, row_ptr, rank, csr_src, ET);

  // ---- layer 1 (4 heads x 32): H1(fp16) = x @ Weff + beff (encode folded) ----
  gemm_k<128, true, 4, true><<<gGemm, b256, 0, stream>>>(x, Weff, beff, as1, ad1,
                                                         es, ed, nullptr, Hh, N_);
  aggr_csr_k<4, 32, true, true><<<gAggr, b256, 0, stream>>>(nullptr, Hh, es, ed,
                                                            row_ptr, csr_src, b1,
                                                            bufA, N_);

  // ---- layer 2 (4 heads x 32): H2 in fp16 ----
  gemm_k<128, false, 4, true><<<gGemm, b256, 0, stream>>>(bufA, W2, nullptr, as2, ad2,
                                                          es, ed, nullptr, Hh, N_);
  aggr_csr_k<4, 32, true, true><<<gAggr, b256, 0, stream>>>(nullptr, Hh, es, ed,
                                                            row_ptr, csr_src, b2,
                                                            bufA, N_);

  // ---- layer 3 (1 head x 64): H3 fp32 (feeds output directly) ----
  gemm_k<64, false, 1, false><<<gGemm, b256, 0, stream>>>(bufA, W3, nullptr, as3, ad3,
                                                          es, ed, bufB, nullptr, N_);
  aggr_csr_k<1, 64, false, false><<<gAggr, b256, 0, stream>>>(bufB, nullptr, es, ed,
                                                              row_ptr, csr_src, b3,
                                                              out, N_);
}

// Round 12
// 641.607 us; speedup vs baseline: 7.7455x; 1.0457x over previous
//
#include <hip/hip_runtime.h>
#include <hip/hip_fp16.h>

// GAT via device-built CSR. Encode GEMM folded into layer-1 (W_eff = Ew@W1).
// Layers 1/2: GEMM writes H as fp16 ONLY; es/ed from fp32 accs in epilogue.
// CSR: rank-based counting sort (atomic-free fill).
// Aggregation: single-pass no-max softmax, one 16-lane group per dst,
// DUAL edge pipeline (2 edges/iter, depth-2 prefetch = 4 gathers in flight).

// ------- GEMM: (+bias) (+es/ed epilogue) (+fp16 or fp32 H output) -------
template <int OUTC, bool BIAS, int NH, bool HOUT>
__global__ __launch_bounds__(256) void gemm_k(const float* __restrict__ X,
                                              const float* __restrict__ W,
                                              const float* __restrict__ B,
                                              const float* __restrict__ AS,
                                              const float* __restrict__ AD,
                                              float* __restrict__ es,
                                              float* __restrict__ ed,
                                              float* __restrict__ Y,
                                              __half* __restrict__ Hh, int n) {
  __shared__ float sW[128 * OUTC];
  __shared__ float sX[32 * 128];
  for (int i = threadIdx.x * 4; i < 128 * OUTC; i += 256 * 4)
    *(float4*)&sW[i] = *(const float4*)&W[i];
  int row0 = blockIdx.x * 32;
  for (int i = threadIdx.x * 4; i < 32 * 128; i += 256 * 4) {
    int r = i >> 7, c = i & 127;
    int gr = row0 + r;
    float4 v = make_float4(0.f, 0.f, 0.f, 0.f);
    if (gr < n) v = *(const float4*)&X[(size_t)gr * 128 + c];
    *(float4*)&sX[i] = v;
  }
  __syncthreads();
  const int tx = threadIdx.x & 31;
  const int ty = threadIdx.x >> 5;
  constexpr int CPT = OUTC / 32;
  const int c0 = tx * CPT;
  const int r0 = ty * 4;
  float acc[4][CPT];
#pragma unroll
  for (int r = 0; r < 4; r++)
#pragma unroll
    for (int c = 0; c < CPT; c++) acc[r][c] = 0.f;

#pragma unroll 2
  for (int k = 0; k < 128; k += 4) {
    float4 xv0 = *(float4*)&sX[(r0 + 0) * 128 + k];
    float4 xv1 = *(float4*)&sX[(r0 + 1) * 128 + k];
    float4 xv2 = *(float4*)&sX[(r0 + 2) * 128 + k];
    float4 xv3 = *(float4*)&sX[(r0 + 3) * 128 + k];
#pragma unroll
    for (int kk = 0; kk < 4; kk++) {
      float w[CPT];
#pragma unroll
      for (int c = 0; c < CPT; c++) w[c] = sW[(k + kk) * OUTC + c0 + c];
      float x0 = (&xv0.x)[kk], x1 = (&xv1.x)[kk], x2 = (&xv2.x)[kk], x3 = (&xv3.x)[kk];
#pragma unroll
      for (int c = 0; c < CPT; c++) {
        acc[0][c] = fmaf(x0, w[c], acc[0][c]);
        acc[1][c] = fmaf(x1, w[c], acc[1][c]);
        acc[2][c] = fmaf(x2, w[c], acc[2][c]);
        acc[3][c] = fmaf(x3, w[c], acc[3][c]);
      }
    }
  }
  // fold bias into acc once
  if constexpr (BIAS) {
#pragma unroll
    for (int r = 0; r < 4; r++)
#pragma unroll
      for (int c = 0; c < CPT; c++) acc[r][c] += B[c0 + c];
  }
#pragma unroll
  for (int r = 0; r < 4; r++) {
    int gr = row0 + r0 + r;
    if (gr < n) {
      if constexpr (HOUT) {
        // OUTC==128, CPT==4: pack 4 halves (8B)
        __half2 p0 = __floats2half2_rn(acc[r][0], acc[r][1]);
        __half2 p1 = __floats2half2_rn(acc[r][2], acc[r][3]);
        uint2 pk;
        pk.x = *reinterpret_cast<unsigned*>(&p0);
        pk.y = *reinterpret_cast<unsigned*>(&p1);
        *(uint2*)&Hh[(size_t)gr * OUTC + c0] = pk;
      } else {
#pragma unroll
        for (int c = 0; c < CPT; c++)
          Y[(size_t)gr * OUTC + c0 + c] = acc[r][c];
      }
    }
  }
  // ---- fused attention-coefficient epilogue (from fp32 accs) ----
  if constexpr (NH > 0) {
    constexpr int CH = OUTC / NH;
    constexpr int GRP = CH / CPT;  // lanes per head group (8 or 32)
    float asv[CPT], adv[CPT];
#pragma unroll
    for (int c = 0; c < CPT; c++) { asv[c] = AS[c0 + c]; adv[c] = AD[c0 + c]; }
#pragma unroll
    for (int r = 0; r < 4; r++) {
      float ps = 0.f, pd = 0.f;
#pragma unroll
      for (int c = 0; c < CPT; c++) {
        ps = fmaf(acc[r][c], asv[c], ps);
        pd = fmaf(acc[r][c], adv[c], pd);
      }
#pragma unroll
      for (int off = 1; off < GRP; off <<= 1) {
        ps += __shfl_xor(ps, off, 64);
        pd += __shfl_xor(pd, off, 64);
      }
      int gr = row0 + r0 + r;
      if (gr < n && (tx & (GRP - 1)) == 0) {
        int hh = tx / GRP;
        es[(size_t)gr * NH + hh] = ps;
        ed[(size_t)gr * NH + hh] = pd;
      }
    }
  }
}

// ---------------- weight fold: Weff = EW @ W1, beff = EB @ W1 ----------------
__global__ __launch_bounds__(256) void wfold_k(const float* __restrict__ EW,
                                               const float* __restrict__ W1,
                                               const float* __restrict__ EB,
                                               float* __restrict__ Weff,
                                               float* __restrict__ beff) {
  if (blockIdx.x == 16) {
    int c = threadIdx.x;
    if (c < 128) {
      float acc = 0.f;
      for (int k = 0; k < 128; k++) acc = fmaf(EB[k], W1[k * 128 + c], acc);
      beff[c] = acc;
    }
    return;
  }
  int row = blockIdx.x * 8 + (threadIdx.x >> 5);
  int c0 = (threadIdx.x & 31) * 4;
  float4 acc = make_float4(0.f, 0.f, 0.f, 0.f);
  for (int k = 0; k < 128; k++) {
    float xv = EW[row * 128 + k];
    float4 wv = *(const float4*)&W1[k * 128 + c0];
    acc.x = fmaf(xv, wv.x, acc.x);
    acc.y = fmaf(xv, wv.y, acc.y);
    acc.z = fmaf(xv, wv.z, acc.z);
    acc.w = fmaf(xv, wv.w, acc.w);
  }
  *(float4*)&Weff[row * 128 + c0] = acc;
}

// ---------------- CSR build (rank-based counting sort) ----------------
__global__ __launch_bounds__(256) void rank_k(const int* __restrict__ dst,
                                              int* __restrict__ cnt,
                                              int* __restrict__ rank, int ET) {
  int e = blockIdx.x * 256 + threadIdx.x;
  if (e < ET) rank[e] = atomicAdd(&cnt[dst[e]], 1);
}

__global__ __launch_bounds__(256) void block_scan_k(const int* __restrict__ cnt,
                                                    int* __restrict__ row_ptr,
                                                    int* __restrict__ bsum, int n) {
  __shared__ int s[256];
  int t = threadIdx.x;
  int idx = blockIdx.x * 256 + t;
  int val = (idx < n) ? cnt[idx] : 0;
  s[t] = val;
  __syncthreads();
  for (int off = 1; off < 256; off <<= 1) {
    int x = (t >= off) ? s[t - off] : 0;
    __syncthreads();
    s[t] += x;
    __syncthreads();
  }
  if (idx < n) row_ptr[idx] = s[t] - val;  // exclusive
  if (t == 255) bsum[blockIdx.x] = s[255];
}

__global__ __launch_bounds__(512) void bsum_scan_k(int* __restrict__ bsum, int nb) {
  __shared__ int s[512];
  int t = threadIdx.x;
  int v = (t < nb) ? bsum[t] : 0;
  s[t] = v;
  __syncthreads();
  for (int off = 1; off < 512; off <<= 1) {
    int x = (t >= off) ? s[t - off] : 0;
    __syncthreads();
    s[t] += x;
    __syncthreads();
  }
  if (t < nb) bsum[t] = s[t] - v;  // exclusive
}

__global__ __launch_bounds__(256) void add_off_k(int* __restrict__ row_ptr,
                                                 const int* __restrict__ bsum,
                                                 int n, int ET) {
  int idx = blockIdx.x * 256 + threadIdx.x;
  if (idx < n) row_ptr[idx] += bsum[idx >> 8];
  if (idx == 0) row_ptr[n] = ET;
}

__global__ __launch_bounds__(256) void fill_k(const int* __restrict__ src,
                                              const int* __restrict__ dst,
                                              const int* __restrict__ row_ptr,
                                              const int* __restrict__ rank,
                                              int* __restrict__ csr_src, int ET) {
  int e = blockIdx.x * 256 + threadIdx.x;
  if (e >= ET) return;
  csr_src[row_ptr[dst[e]] + rank[e]] = src[e];
}

// -------- fused segment softmax + aggregation: one 16-lane group per dst ------
// Both variants have 256B rows: HALF = 128ch fp16, !HALF = 64ch fp32.
// Dual edge pipeline: 2 edges/iter with independent states + depth-2 prefetch.
template <int NH, bool RELU, bool HALF>
__global__ __launch_bounds__(256) void aggr_csr_k(const void* __restrict__ Hrow,
                                                  const float* __restrict__ es,
                                                  const float* __restrict__ ed,
                                                  const int* __restrict__ row_ptr,
                                                  const int* __restrict__ csr_src,
                                                  const float* __restrict__ bias,
                                                  float* __restrict__ out, int n) {
  constexpr int NC = HALF ? 128 : 64;
  constexpr int CPL = HALF ? 8 : 4;   // elements per lane (16B)

  const int g = threadIdx.x >> 4;
  const int d = blockIdx.x * 16 + g;
  if (d >= n) return;
  const int gl = threadIdx.x & 15;
  const int ch0 = gl * CPL;
  const int head = (NH == 4) ? (ch0 >> 5) : 0;
  const int beg = row_ptr[d];
  const int deg = row_ptr[d + 1] - beg;  // >= 1 (self-loops)
  const float ed_h = ed[(size_t)d * NH + head];
  const char* __restrict__ Hb = (const char*)Hrow;

  float den = 0.f;
  float a[CPL];
#pragma unroll
  for (int c = 0; c < CPL; c++) a[c] = 0.f;

  // clamped load: invalid idx -> e=-1e30 (ex underflows to 0), safe row read
  auto loadE = [&](int idx, float& e, uint4& h) {
    bool valid = idx < deg;
    int ii = valid ? beg + idx : beg;
    int ss = csr_src[ii];
    e = valid ? es[(size_t)ss * NH + head] : -1e30f;
    h = *(const uint4*)(Hb + (size_t)ss * 256 + gl * 16);
  };
  auto consume = [&](float e, const uint4& h) {
    float vv = e + ed_h;
    vv = vv >= 0.f ? vv : 0.2f * vv;  // leaky relu
    float ex = __expf(vv);            // no max-sub: args are O(1)
    den += ex;
    if constexpr (HALF) {
      const unsigned* u = &h.x;
#pragma unroll
      for (int q = 0; q < 4; q++) {
        __half2 h2 = *reinterpret_cast<const __half2*>(&u[q]);
        float2 f2 = __half22float2(h2);
        a[2 * q]     = fmaf(f2.x, ex, a[2 * q]);
        a[2 * q + 1] = fmaf(f2.y, ex, a[2 * q + 1]);
      }
    } else {
      const float4 f = *reinterpret_cast<const float4*>(&h);
      a[0] = fmaf(f.x, ex, a[0]);
      a[1] = fmaf(f.y, ex, a[1]);
      a[2] = fmaf(f.z, ex, a[2]);
      a[3] = fmaf(f.w, ex, a[3]);
    }
  };

  float eA, eB;
  uint4 hA, hB;
  loadE(0, eA, hA);
  loadE(1, eB, hB);
  for (int i = 0; i < deg; i += 2) {
    float eA2 = -1e30f, eB2 = -1e30f;
    uint4 hA2 = make_uint4(0, 0, 0, 0), hB2 = hA2;
    if (i + 2 < deg) {  // group-uniform; exec-masked, no wasted traffic
      loadE(i + 2, eA2, hA2);
      loadE(i + 3, eB2, hB2);
    }
    consume(eA, hA);
    consume(eB, hB);
    eA = eA2; hA = hA2;
    eB = eB2; hB = hB2;
  }

  float inv = 1.f / den;
#pragma unroll
  for (int q = 0; q < CPL / 4; q++) {
    float4 bv = *(const float4*)&bias[ch0 + 4 * q];
    float4 o;
    o.x = fmaf(a[4 * q + 0], inv, bv.x);
    o.y = fmaf(a[4 * q + 1], inv, bv.y);
    o.z = fmaf(a[4 * q + 2], inv, bv.z);
    o.w = fmaf(a[4 * q + 3], inv, bv.w);
    if (RELU) {
      o.x = fmaxf(o.x, 0.f); o.y = fmaxf(o.y, 0.f);
      o.z = fmaxf(o.z, 0.f); o.w = fmaxf(o.w, 0.f);
    }
    *(float4*)&out[(size_t)d * NC + ch0 + 4 * q] = o;
  }
}

extern "C" void kernel_launch(void* const* d_in, const int* in_sizes, int n_in,
                              void* d_out, int out_size, void* d_ws, size_t ws_size,
                              hipStream_t stream) {
  const float* x = (const float*)d_in[0];
  const float* encw = (const float*)d_in[2];
  const float* encb = (const float*)d_in[3];
  const float* W1 = (const float*)d_in[4];
  const float* as1 = (const float*)d_in[5];
  const float* ad1 = (const float*)d_in[6];
  const float* b1 = (const float*)d_in[7];
  const float* W2 = (const float*)d_in[8];
  const float* as2 = (const float*)d_in[9];
  const float* ad2 = (const float*)d_in[10];
  const float* b2 = (const float*)d_in[11];
  const float* W3 = (const float*)d_in[12];
  const float* as3 = (const float*)d_in[13];
  const float* ad3 = (const float*)d_in[14];
  const float* b3 = (const float*)d_in[15];
  const int* ei = (const int*)d_in[16];

  const int N_ = in_sizes[0] / 128;
  const int ET = in_sizes[16] / 2;
  const int* srcp = ei;
  const int* dstp = ei + ET;
  float* out = (float*)d_out;

  // workspace carve-up (Hh aliases bufB; rank aliases bufB too — rank is dead
  // before GEMM1 writes Hh, single stream so no hazard)
  size_t NB = (size_t)N_ * 128 * sizeof(float);
  char* p = (char*)d_ws;
  float* bufA = (float*)p;      p += NB;
  float* bufB = (float*)p;      p += NB;
  __half* Hh = (__half*)bufB;   // fp16 H for layers 1/2
  int* rank = (int*)bufB;       // per-edge rank during CSR build (ET ints)
  float* es = (float*)p;        p += (size_t)N_ * 4 * sizeof(float);
  float* ed = (float*)p;        p += (size_t)N_ * 4 * sizeof(float);
  int* cnt = (int*)p;           p += (size_t)N_ * sizeof(int);
  int* row_ptr = (int*)p;       p += (size_t)(N_ + 1) * sizeof(int);
  int* bsum = (int*)p;          p += (size_t)((N_ + 255) / 256) * sizeof(int);
  int* csr_src = (int*)p;       p += (size_t)ET * sizeof(int);
  float* Weff = (float*)p;      p += (size_t)128 * 128 * sizeof(float);
  float* beff = (float*)p;      p += (size_t)128 * sizeof(float);

  dim3 b256(256);
  int gGemm = (N_ + 31) / 32;
  int gNode = (N_ + 255) / 256;
  int gEdge = (ET + 255) / 256;
  int gAggr = (N_ + 15) / 16;
  int nb = (N_ + 255) / 256;

  // ---- weight fold (tiny) + CSR build ----
  wfold_k<<<17, b256, 0, stream>>>(encw, W1, encb, Weff, beff);
  hipMemsetAsync(cnt, 0, (size_t)N_ * sizeof(int), stream);
  rank_k<<<gEdge, b256, 0, stream>>>(dstp, cnt, rank, ET);
  block_scan_k<<<nb, b256, 0, stream>>>(cnt, row_ptr, bsum, N_);
  bsum_scan_k<<<1, 512, 0, stream>>>(bsum, nb);
  add_off_k<<<gNode, b256, 0, stream>>>(row_ptr, bsum, N_, ET);
  fill_k<<<gEdge, b256, 0, stream>>>(srcp, dstp, row_ptr, rank, csr_src, ET);

  // ---- layer 1 (4 heads x 32): H1(fp16) = x @ Weff + beff (encode folded) ----
  gemm_k<128, true, 4, true><<<gGemm, b256, 0, stream>>>(x, Weff, beff, as1, ad1,
                                                         es, ed, nullptr, Hh, N_);
  aggr_csr_k<4, true, true><<<gAggr, b256, 0, stream>>>(Hh, es, ed, row_ptr,
                                                        csr_src, b1, bufA, N_);

  // ---- layer 2 (4 heads x 32): H2 in fp16 ----
  gemm_k<128, false, 4, true><<<gGemm, b256, 0, stream>>>(bufA, W2, nullptr, as2, ad2,
                                                          es, ed, nullptr, Hh, N_);
  aggr_csr_k<4, true, true><<<gAggr, b256, 0, stream>>>(Hh, es, ed, row_ptr,
                                                        csr_src, b2, bufA, N_);

  // ---- layer 3 (1 head x 64): H3 fp32 (feeds output directly) ----
  gemm_k<64, false, 1, false><<<gGemm, b256, 0, stream>>>(bufA, W3, nullptr, as3, ad3,
                                                          es, ed, bufB, nullptr, N_);
  aggr_csr_k<1, false, false><<<gAggr, b256, 0, stream>>>(bufB, es, ed, row_ptr,
                                                          csr_src, b3, out, N_);
}

// Round 13
// 609.887 us; speedup vs baseline: 8.1483x; 1.0520x over previous
//
#include <hip/hip_runtime.h>
#include <hip/hip_fp16.h>

// GAT via device-built CSR. Encode GEMM folded into layer-1 (W_eff = Ew@W1).
// Layers 1/2: GEMM writes H as fp16 ONLY; es/ed from fp32 accs in epilogue.
// GEMM: K-chunked W staging (32KB LDS -> 5 blocks/CU, was 80KB -> 2).
// CSR: rank-based counting sort (atomic-free fill).
// Aggregation: single-pass no-max softmax, 16-lane group per dst, dual pipeline.

// ------- GEMM: (+bias) (+es/ed epilogue) (+fp16 or fp32 H output) -------
template <int OUTC, bool BIAS, int NH, bool HOUT>
__global__ __launch_bounds__(256) void gemm_k(const float* __restrict__ X,
                                              const float* __restrict__ W,
                                              const float* __restrict__ B,
                                              const float* __restrict__ AS,
                                              const float* __restrict__ AD,
                                              float* __restrict__ es,
                                              float* __restrict__ ed,
                                              float* __restrict__ Y,
                                              __half* __restrict__ Hh, int n) {
  __shared__ float sW[32 * OUTC];   // K-chunk of W (16KB / 8KB)
  __shared__ float sX[32 * 128];    // full X tile (16KB)
  int row0 = blockIdx.x * 32;
  for (int i = threadIdx.x * 4; i < 32 * 128; i += 256 * 4) {
    int r = i >> 7, c = i & 127;
    int gr = row0 + r;
    float4 v = make_float4(0.f, 0.f, 0.f, 0.f);
    if (gr < n) v = *(const float4*)&X[(size_t)gr * 128 + c];
    *(float4*)&sX[i] = v;
  }
  const int tx = threadIdx.x & 31;
  const int ty = threadIdx.x >> 5;
  constexpr int CPT = OUTC / 32;
  const int c0 = tx * CPT;
  const int r0 = ty * 4;
  float acc[4][CPT];
#pragma unroll
  for (int r = 0; r < 4; r++)
#pragma unroll
    for (int c = 0; c < CPT; c++) acc[r][c] = 0.f;

  for (int kc = 0; kc < 128; kc += 32) {
    __syncthreads();  // protect sW reuse (also covers initial sX stage)
    for (int i = threadIdx.x * 4; i < 32 * OUTC; i += 256 * 4)
      *(float4*)&sW[i] = *(const float4*)&W[kc * OUTC + i];
    __syncthreads();
#pragma unroll 2
    for (int kk4 = 0; kk4 < 32; kk4 += 4) {
      int k = kc + kk4;
      float4 xv0 = *(float4*)&sX[(r0 + 0) * 128 + k];
      float4 xv1 = *(float4*)&sX[(r0 + 1) * 128 + k];
      float4 xv2 = *(float4*)&sX[(r0 + 2) * 128 + k];
      float4 xv3 = *(float4*)&sX[(r0 + 3) * 128 + k];
#pragma unroll
      for (int kk = 0; kk < 4; kk++) {
        float w[CPT];
#pragma unroll
        for (int c = 0; c < CPT; c++) w[c] = sW[(kk4 + kk) * OUTC + c0 + c];
        float x0 = (&xv0.x)[kk], x1 = (&xv1.x)[kk], x2 = (&xv2.x)[kk], x3 = (&xv3.x)[kk];
#pragma unroll
        for (int c = 0; c < CPT; c++) {
          acc[0][c] = fmaf(x0, w[c], acc[0][c]);
          acc[1][c] = fmaf(x1, w[c], acc[1][c]);
          acc[2][c] = fmaf(x2, w[c], acc[2][c]);
          acc[3][c] = fmaf(x3, w[c], acc[3][c]);
        }
      }
    }
  }
  // fold bias into acc once
  if constexpr (BIAS) {
#pragma unroll
    for (int r = 0; r < 4; r++)
#pragma unroll
      for (int c = 0; c < CPT; c++) acc[r][c] += B[c0 + c];
  }
#pragma unroll
  for (int r = 0; r < 4; r++) {
    int gr = row0 + r0 + r;
    if (gr < n) {
      if constexpr (HOUT) {
        // OUTC==128, CPT==4: pack 4 halves (8B)
        __half2 p0 = __floats2half2_rn(acc[r][0], acc[r][1]);
        __half2 p1 = __floats2half2_rn(acc[r][2], acc[r][3]);
        uint2 pk;
        pk.x = *reinterpret_cast<unsigned*>(&p0);
        pk.y = *reinterpret_cast<unsigned*>(&p1);
        *(uint2*)&Hh[(size_t)gr * OUTC + c0] = pk;
      } else {
#pragma unroll
        for (int c = 0; c < CPT; c++)
          Y[(size_t)gr * OUTC + c0 + c] = acc[r][c];
      }
    }
  }
  // ---- fused attention-coefficient epilogue (from fp32 accs) ----
  if constexpr (NH > 0) {
    constexpr int CH = OUTC / NH;
    constexpr int GRP = CH / CPT;  // lanes per head group (8 or 32)
    float asv[CPT], adv[CPT];
#pragma unroll
    for (int c = 0; c < CPT; c++) { asv[c] = AS[c0 + c]; adv[c] = AD[c0 + c]; }
#pragma unroll
    for (int r = 0; r < 4; r++) {
      float ps = 0.f, pd = 0.f;
#pragma unroll
      for (int c = 0; c < CPT; c++) {
        ps = fmaf(acc[r][c], asv[c], ps);
        pd = fmaf(acc[r][c], adv[c], pd);
      }
#pragma unroll
      for (int off = 1; off < GRP; off <<= 1) {
        ps += __shfl_xor(ps, off, 64);
        pd += __shfl_xor(pd, off, 64);
      }
      int gr = row0 + r0 + r;
      if (gr < n && (tx & (GRP - 1)) == 0) {
        int hh = tx / GRP;
        es[(size_t)gr * NH + hh] = ps;
        ed[(size_t)gr * NH + hh] = pd;
      }
    }
  }
}

// ---------------- weight fold: Weff = EW @ W1, beff = EB @ W1 ----------------
__global__ __launch_bounds__(256) void wfold_k(const float* __restrict__ EW,
                                               const float* __restrict__ W1,
                                               const float* __restrict__ EB,
                                               float* __restrict__ Weff,
                                               float* __restrict__ beff) {
  if (blockIdx.x == 16) {
    int c = threadIdx.x;
    if (c < 128) {
      float acc = 0.f;
      for (int k = 0; k < 128; k++) acc = fmaf(EB[k], W1[k * 128 + c], acc);
      beff[c] = acc;
    }
    return;
  }
  int row = blockIdx.x * 8 + (threadIdx.x >> 5);
  int c0 = (threadIdx.x & 31) * 4;
  float4 acc = make_float4(0.f, 0.f, 0.f, 0.f);
  for (int k = 0; k < 128; k++) {
    float xv = EW[row * 128 + k];
    float4 wv = *(const float4*)&W1[k * 128 + c0];
    acc.x = fmaf(xv, wv.x, acc.x);
    acc.y = fmaf(xv, wv.y, acc.y);
    acc.z = fmaf(xv, wv.z, acc.z);
    acc.w = fmaf(xv, wv.w, acc.w);
  }
  *(float4*)&Weff[row * 128 + c0] = acc;
}

// ---------------- CSR build (rank-based counting sort) ----------------
__global__ __launch_bounds__(256) void rank_k(const int* __restrict__ dst,
                                              int* __restrict__ cnt,
                                              int* __restrict__ rank, int ET) {
  int e = blockIdx.x * 256 + threadIdx.x;
  if (e < ET) rank[e] = atomicAdd(&cnt[dst[e]], 1);
}

__global__ __launch_bounds__(256) void block_scan_k(const int* __restrict__ cnt,
                                                    int* __restrict__ row_ptr,
                                                    int* __restrict__ bsum, int n) {
  __shared__ int s[256];
  int t = threadIdx.x;
  int idx = blockIdx.x * 256 + t;
  int val = (idx < n) ? cnt[idx] : 0;
  s[t] = val;
  __syncthreads();
  for (int off = 1; off < 256; off <<= 1) {
    int x = (t >= off) ? s[t - off] : 0;
    __syncthreads();
    s[t] += x;
    __syncthreads();
  }
  if (idx < n) row_ptr[idx] = s[t] - val;  // exclusive
  if (t == 255) bsum[blockIdx.x] = s[255];
}

__global__ __launch_bounds__(512) void bsum_scan_k(int* __restrict__ bsum, int nb) {
  __shared__ int s[512];
  int t = threadIdx.x;
  int v = (t < nb) ? bsum[t] : 0;
  s[t] = v;
  __syncthreads();
  for (int off = 1; off < 512; off <<= 1) {
    int x = (t >= off) ? s[t - off] : 0;
    __syncthreads();
    s[t] += x;
    __syncthreads();
  }
  if (t < nb) bsum[t] = s[t] - v;  // exclusive
}

__global__ __launch_bounds__(256) void add_off_k(int* __restrict__ row_ptr,
                                                 const int* __restrict__ bsum,
                                                 int n, int ET) {
  int idx = blockIdx.x * 256 + threadIdx.x;
  if (idx < n) row_ptr[idx] += bsum[idx >> 8];
  if (idx == 0) row_ptr[n] = ET;
}

__global__ __launch_bounds__(256) void fill_k(const int* __restrict__ src,
                                              const int* __restrict__ dst,
                                              const int* __restrict__ row_ptr,
                                              const int* __restrict__ rank,
                                              int* __restrict__ csr_src, int ET) {
  int e = blockIdx.x * 256 + threadIdx.x;
  if (e >= ET) return;
  csr_src[row_ptr[dst[e]] + rank[e]] = src[e];
}

// -------- fused segment softmax + aggregation: one 16-lane group per dst ------
// Both variants have 256B rows: HALF = 128ch fp16, !HALF = 64ch fp32.
// Dual edge pipeline: 2 edges/iter with independent states + depth-2 prefetch.
template <int NH, bool RELU, bool HALF>
__global__ __launch_bounds__(256) void aggr_csr_k(const void* __restrict__ Hrow,
                                                  const float* __restrict__ es,
                                                  const float* __restrict__ ed,
                                                  const int* __restrict__ row_ptr,
                                                  const int* __restrict__ csr_src,
                                                  const float* __restrict__ bias,
                                                  float* __restrict__ out, int n) {
  constexpr int NC = HALF ? 128 : 64;
  constexpr int CPL = HALF ? 8 : 4;   // elements per lane (16B)

  const int g = threadIdx.x >> 4;
  const int d = blockIdx.x * 16 + g;
  if (d >= n) return;
  const int gl = threadIdx.x & 15;
  const int ch0 = gl * CPL;
  const int head = (NH == 4) ? (ch0 >> 5) : 0;
  const int beg = row_ptr[d];
  const int deg = row_ptr[d + 1] - beg;  // >= 1 (self-loops)
  const float ed_h = ed[(size_t)d * NH + head];
  const char* __restrict__ Hb = (const char*)Hrow;

  float den = 0.f;
  float a[CPL];
#pragma unroll
  for (int c = 0; c < CPL; c++) a[c] = 0.f;

  // clamped load: invalid idx -> e=-1e30 (ex underflows to 0), safe row read
  auto loadE = [&](int idx, float& e, uint4& h) {
    bool valid = idx < deg;
    int ii = valid ? beg + idx : beg;
    int ss = csr_src[ii];
    e = valid ? es[(size_t)ss * NH + head] : -1e30f;
    h = *(const uint4*)(Hb + (size_t)ss * 256 + gl * 16);
  };
  auto consume = [&](float e, const uint4& h) {
    float vv = e + ed_h;
    vv = vv >= 0.f ? vv : 0.2f * vv;  // leaky relu
    float ex = __expf(vv);            // no max-sub: args are O(1)
    den += ex;
    if constexpr (HALF) {
      const unsigned* u = &h.x;
#pragma unroll
      for (int q = 0; q < 4; q++) {
        __half2 h2 = *reinterpret_cast<const __half2*>(&u[q]);
        float2 f2 = __half22float2(h2);
        a[2 * q]     = fmaf(f2.x, ex, a[2 * q]);
        a[2 * q + 1] = fmaf(f2.y, ex, a[2 * q + 1]);
      }
    } else {
      const float4 f = *reinterpret_cast<const float4*>(&h);
      a[0] = fmaf(f.x, ex, a[0]);
      a[1] = fmaf(f.y, ex, a[1]);
      a[2] = fmaf(f.z, ex, a[2]);
      a[3] = fmaf(f.w, ex, a[3]);
    }
  };

  float eA, eB;
  uint4 hA, hB;
  loadE(0, eA, hA);
  loadE(1, eB, hB);
  for (int i = 0; i < deg; i += 2) {
    float eA2 = -1e30f, eB2 = -1e30f;
    uint4 hA2 = make_uint4(0, 0, 0, 0), hB2 = hA2;
    if (i + 2 < deg) {  // group-uniform; exec-masked, no wasted traffic
      loadE(i + 2, eA2, hA2);
      loadE(i + 3, eB2, hB2);
    }
    consume(eA, hA);
    consume(eB, hB);
    eA = eA2; hA = hA2;
    eB = eB2; hB = hB2;
  }

  float inv = 1.f / den;
#pragma unroll
  for (int q = 0; q < CPL / 4; q++) {
    float4 bv = *(const float4*)&bias[ch0 + 4 * q];
    float4 o;
    o.x = fmaf(a[4 * q + 0], inv, bv.x);
    o.y = fmaf(a[4 * q + 1], inv, bv.y);
    o.z = fmaf(a[4 * q + 2], inv, bv.z);
    o.w = fmaf(a[4 * q + 3], inv, bv.w);
    if (RELU) {
      o.x = fmaxf(o.x, 0.f); o.y = fmaxf(o.y, 0.f);
      o.z = fmaxf(o.z, 0.f); o.w = fmaxf(o.w, 0.f);
    }
    *(float4*)&out[(size_t)d * NC + ch0 + 4 * q] = o;
  }
}

extern "C" void kernel_launch(void* const* d_in, const int* in_sizes, int n_in,
                              void* d_out, int out_size, void* d_ws, size_t ws_size,
                              hipStream_t stream) {
  const float* x = (const float*)d_in[0];
  const float* encw = (const float*)d_in[2];
  const float* encb = (const float*)d_in[3];
  const float* W1 = (const float*)d_in[4];
  const float* as1 = (const float*)d_in[5];
  const float* ad1 = (const float*)d_in[6];
  const float* b1 = (const float*)d_in[7];
  const float* W2 = (const float*)d_in[8];
  const float* as2 = (const float*)d_in[9];
  const float* ad2 = (const float*)d_in[10];
  const float* b2 = (const float*)d_in[11];
  const float* W3 = (const float*)d_in[12];
  const float* as3 = (const float*)d_in[13];
  const float* ad3 = (const float*)d_in[14];
  const float* b3 = (const float*)d_in[15];
  const int* ei = (const int*)d_in[16];

  const int N_ = in_sizes[0] / 128;
  const int ET = in_sizes[16] / 2;
  const int* srcp = ei;
  const int* dstp = ei + ET;
  float* out = (float*)d_out;

  // workspace carve-up (Hh aliases bufB; rank aliases bufB too — rank is dead
  // before GEMM1 writes Hh, single stream so no hazard)
  size_t NB = (size_t)N_ * 128 * sizeof(float);
  char* p = (char*)d_ws;
  float* bufA = (float*)p;      p += NB;
  float* bufB = (float*)p;      p += NB;
  __half* Hh = (__half*)bufB;   // fp16 H for layers 1/2
  int* rank = (int*)bufB;       // per-edge rank during CSR build (ET ints)
  float* es = (float*)p;        p += (size_t)N_ * 4 * sizeof(float);
  float* ed = (float*)p;        p += (size_t)N_ * 4 * sizeof(float);
  int* cnt = (int*)p;           p += (size_t)N_ * sizeof(int);
  int* row_ptr = (int*)p;       p += (size_t)(N_ + 1) * sizeof(int);
  int* bsum = (int*)p;          p += (size_t)((N_ + 255) / 256) * sizeof(int);
  int* csr_src = (int*)p;       p += (size_t)ET * sizeof(int);
  float* Weff = (float*)p;      p += (size_t)128 * 128 * sizeof(float);
  float* beff = (float*)p;      p += (size_t)128 * sizeof(float);

  dim3 b256(256);
  int gGemm = (N_ + 31) / 32;
  int gNode = (N_ + 255) / 256;
  int gEdge = (ET + 255) / 256;
  int gAggr = (N_ + 15) / 16;
  int nb = (N_ + 255) / 256;

  // ---- weight fold (tiny) + CSR build ----
  wfold_k<<<17, b256, 0, stream>>>(encw, W1, encb, Weff, beff);
  hipMemsetAsync(cnt, 0, (size_t)N_ * sizeof(int), stream);
  rank_k<<<gEdge, b256, 0, stream>>>(dstp, cnt, rank, ET);
  block_scan_k<<<nb, b256, 0, stream>>>(cnt, row_ptr, bsum, N_);
  bsum_scan_k<<<1, 512, 0, stream>>>(bsum, nb);
  add_off_k<<<gNode, b256, 0, stream>>>(row_ptr, bsum, N_, ET);
  fill_k<<<gEdge, b256, 0, stream>>>(srcp, dstp, row_ptr, rank, csr_src, ET);

  // ---- layer 1 (4 heads x 32): H1(fp16) = x @ Weff + beff (encode folded) ----
  gemm_k<128, true, 4, true><<<gGemm, b256, 0, stream>>>(x, Weff, beff, as1, ad1,
                                                         es, ed, nullptr, Hh, N_);
  aggr_csr_k<4, true, true><<<gAggr, b256, 0, stream>>>(Hh, es, ed, row_ptr,
                                                        csr_src, b1, bufA, N_);

  // ---- layer 2 (4 heads x 32): H2 in fp16 ----
  gemm_k<128, false, 4, true><<<gGemm, b256, 0, stream>>>(bufA, W2, nullptr, as2, ad2,
                                                          es, ed, nullptr, Hh, N_);
  aggr_csr_k<4, true, true><<<gAggr, b256, 0, stream>>>(Hh, es, ed, row_ptr,
                                                        csr_src, b2, bufA, N_);

  // ---- layer 3 (1 head x 64): H3 fp32 (feeds output directly) ----
  gemm_k<64, false, 1, false><<<gGemm, b256, 0, stream>>>(bufA, W3, nullptr, as3, ad3,
                                                          es, ed, bufB, nullptr, N_);
  aggr_csr_k<1, false, false><<<gAggr, b256, 0, stream>>>(bufB, es, ed, row_ptr,
                                                          csr_src, b3, out, N_);
}

// Round 14
// 565.705 us; speedup vs baseline: 8.7847x; 1.0781x over previous
//
#include <hip/hip_runtime.h>
#include <hip/hip_fp16.h>

// GAT via device-built CSR. Encode GEMM folded into layer-1 (W_eff = Ew@W1).
// Layers 1/2: fp16 MFMA GEMM (mfma_f32_16x16x32_f16, fp32 acc), H out fp16,
// es/ed from fp32 accs. Layer 3: fp32 VALU GEMM (feeds output).
// CSR: rank-based counting sort (atomic-free fill).
// Aggregation: single-pass no-max softmax, 16-lane group per dst, dual pipeline.

typedef _Float16 half8_t __attribute__((ext_vector_type(8)));
typedef float f32x4_t __attribute__((ext_vector_type(4)));

// ------- MFMA GEMM (OUTC=128): Y fp16 + es/ed epilogue -------
// Block: 32 rows x 128 cols, 4 waves. Wave: mh=w&1 (16 rows), nq=w>>1 (64 cols).
// Frags: A[lane&15][kg*8+j], B[kg*8+j][lane&15]; D: row=kg*4+r, col=lane&15.
template <bool BIAS>
__global__ __launch_bounds__(256) void gemm_mfma_k(const float* __restrict__ X,
                                                   const __half* __restrict__ Wt,
                                                   const float* __restrict__ B,
                                                   const float* __restrict__ AS,
                                                   const float* __restrict__ AD,
                                                   float* __restrict__ es,
                                                   float* __restrict__ ed,
                                                   __half* __restrict__ Hh, int n) {
  __shared__ __half sX[32 * 136];    // +8 pad: row stride 272B -> bank-safe
  __shared__ __half sWt[128 * 136];  // Wt[col][k], padded
  const int row0 = blockIdx.x * 32;

  // stage X (fp32 -> fp16)
  for (int i = threadIdx.x * 4; i < 32 * 128; i += 1024) {
    int r = i >> 7, c = i & 127;
    int gr = row0 + r;
    float4 v = make_float4(0.f, 0.f, 0.f, 0.f);
    if (gr < n) v = *(const float4*)&X[(size_t)gr * 128 + c];
    __half2 p0 = __floats2half2_rn(v.x, v.y);
    __half2 p1 = __floats2half2_rn(v.z, v.w);
    uint2 pk;
    pk.x = *reinterpret_cast<unsigned*>(&p0);
    pk.y = *reinterpret_cast<unsigned*>(&p1);
    *(uint2*)&sX[r * 136 + c] = pk;
  }
  // stage Wt (already fp16, [128][128] row-major by col)
  for (int i = threadIdx.x * 8; i < 128 * 128; i += 2048) {
    int c = i >> 7, k = i & 127;
    *(uint4*)&sWt[c * 136 + k] = *(const uint4*)&Wt[i];
  }
  __syncthreads();

  const int l = threadIdx.x & 63;
  const int wv = threadIdx.x >> 6;
  const int mh = wv & 1;
  const int nq = wv >> 1;
  const int lrow = l & 15;
  const int kg = l >> 4;

  f32x4_t acc[4];
#pragma unroll
  for (int nt = 0; nt < 4; nt++) acc[nt] = (f32x4_t){0.f, 0.f, 0.f, 0.f};

#pragma unroll
  for (int ks = 0; ks < 4; ks++) {
    half8_t af = *(const half8_t*)&sX[(mh * 16 + lrow) * 136 + ks * 32 + kg * 8];
#pragma unroll
    for (int nt = 0; nt < 4; nt++) {
      int col = nq * 64 + nt * 16 + lrow;
      half8_t bf = *(const half8_t*)&sWt[col * 136 + ks * 32 + kg * 8];
      acc[nt] = __builtin_amdgcn_mfma_f32_16x16x32_f16(af, bf, acc[nt], 0, 0, 0);
    }
  }

  // bias fold + per-lane col coefs
  float asv[4], adv[4];
#pragma unroll
  for (int nt = 0; nt < 4; nt++) {
    int col = nq * 64 + nt * 16 + lrow;
    if (BIAS) {
      float bv = B[col];
#pragma unroll
      for (int r = 0; r < 4; r++) acc[nt][r] += bv;
    }
    asv[nt] = AS[col];
    adv[nt] = AD[col];
  }

  // H fp16 store
#pragma unroll
  for (int r = 0; r < 4; r++) {
    int gr = row0 + mh * 16 + kg * 4 + r;
    if (gr < n) {
#pragma unroll
      for (int nt = 0; nt < 4; nt++) {
        int col = nq * 64 + nt * 16 + lrow;
        Hh[(size_t)gr * 128 + col] = __float2half(acc[nt][r]);
      }
    }
  }
  // es/ed epilogue: head hs covers tiles {2hs, 2hs+1}; 16-lane xor reduce
#pragma unroll
  for (int hs = 0; hs < 2; hs++) {
#pragma unroll
    for (int r = 0; r < 4; r++) {
      float ps = acc[2 * hs][r] * asv[2 * hs] + acc[2 * hs + 1][r] * asv[2 * hs + 1];
      float pd = acc[2 * hs][r] * adv[2 * hs] + acc[2 * hs + 1][r] * adv[2 * hs + 1];
#pragma unroll
      for (int off = 1; off < 16; off <<= 1) {
        ps += __shfl_xor(ps, off, 64);
        pd += __shfl_xor(pd, off, 64);
      }
      int gr = row0 + mh * 16 + kg * 4 + r;
      if (lrow == 0 && gr < n) {
        es[(size_t)gr * 4 + nq * 2 + hs] = ps;
        ed[(size_t)gr * 4 + nq * 2 + hs] = pd;
      }
    }
  }
}

// ------- fp32 VALU GEMM (layer 3, OUTC=64): Y fp32 + es/ed epilogue -------
template <int OUTC, bool BIAS, int NH>
__global__ __launch_bounds__(256) void gemm_k(const float* __restrict__ X,
                                              const float* __restrict__ W,
                                              const float* __restrict__ B,
                                              const float* __restrict__ AS,
                                              const float* __restrict__ AD,
                                              float* __restrict__ es,
                                              float* __restrict__ ed,
                                              float* __restrict__ Y, int n) {
  __shared__ float sW[32 * OUTC];
  __shared__ float sX[32 * 128];
  int row0 = blockIdx.x * 32;
  for (int i = threadIdx.x * 4; i < 32 * 128; i += 256 * 4) {
    int r = i >> 7, c = i & 127;
    int gr = row0 + r;
    float4 v = make_float4(0.f, 0.f, 0.f, 0.f);
    if (gr < n) v = *(const float4*)&X[(size_t)gr * 128 + c];
    *(float4*)&sX[i] = v;
  }
  const int tx = threadIdx.x & 31;
  const int ty = threadIdx.x >> 5;
  constexpr int CPT = OUTC / 32;
  const int c0 = tx * CPT;
  const int r0 = ty * 4;
  float acc[4][CPT];
#pragma unroll
  for (int r = 0; r < 4; r++)
#pragma unroll
    for (int c = 0; c < CPT; c++) acc[r][c] = 0.f;

  for (int kc = 0; kc < 128; kc += 32) {
    __syncthreads();
    for (int i = threadIdx.x * 4; i < 32 * OUTC; i += 256 * 4)
      *(float4*)&sW[i] = *(const float4*)&W[kc * OUTC + i];
    __syncthreads();
#pragma unroll 2
    for (int kk4 = 0; kk4 < 32; kk4 += 4) {
      int k = kc + kk4;
      float4 xv0 = *(float4*)&sX[(r0 + 0) * 128 + k];
      float4 xv1 = *(float4*)&sX[(r0 + 1) * 128 + k];
      float4 xv2 = *(float4*)&sX[(r0 + 2) * 128 + k];
      float4 xv3 = *(float4*)&sX[(r0 + 3) * 128 + k];
#pragma unroll
      for (int kk = 0; kk < 4; kk++) {
        float w[CPT];
#pragma unroll
        for (int c = 0; c < CPT; c++) w[c] = sW[(kk4 + kk) * OUTC + c0 + c];
        float x0 = (&xv0.x)[kk], x1 = (&xv1.x)[kk], x2 = (&xv2.x)[kk], x3 = (&xv3.x)[kk];
#pragma unroll
        for (int c = 0; c < CPT; c++) {
          acc[0][c] = fmaf(x0, w[c], acc[0][c]);
          acc[1][c] = fmaf(x1, w[c], acc[1][c]);
          acc[2][c] = fmaf(x2, w[c], acc[2][c]);
          acc[3][c] = fmaf(x3, w[c], acc[3][c]);
        }
      }
    }
  }
  if constexpr (BIAS) {
#pragma unroll
    for (int r = 0; r < 4; r++)
#pragma unroll
      for (int c = 0; c < CPT; c++) acc[r][c] += B[c0 + c];
  }
#pragma unroll
  for (int r = 0; r < 4; r++) {
    int gr = row0 + r0 + r;
    if (gr < n) {
#pragma unroll
      for (int c = 0; c < CPT; c++)
        Y[(size_t)gr * OUTC + c0 + c] = acc[r][c];
    }
  }
  if constexpr (NH > 0) {
    constexpr int CH = OUTC / NH;
    constexpr int GRP = CH / CPT;
    float asv[CPT], adv[CPT];
#pragma unroll
    for (int c = 0; c < CPT; c++) { asv[c] = AS[c0 + c]; adv[c] = AD[c0 + c]; }
#pragma unroll
    for (int r = 0; r < 4; r++) {
      float ps = 0.f, pd = 0.f;
#pragma unroll
      for (int c = 0; c < CPT; c++) {
        ps = fmaf(acc[r][c], asv[c], ps);
        pd = fmaf(acc[r][c], adv[c], pd);
      }
#pragma unroll
      for (int off = 1; off < GRP; off <<= 1) {
        ps += __shfl_xor(ps, off, 64);
        pd += __shfl_xor(pd, off, 64);
      }
      int gr = row0 + r0 + r;
      if (gr < n && (tx & (GRP - 1)) == 0) {
        int hh = tx / GRP;
        es[(size_t)gr * NH + hh] = ps;
        ed[(size_t)gr * NH + hh] = pd;
      }
    }
  }
}

// ---------------- weight fold: Weff = EW @ W1, beff = EB @ W1 ----------------
__global__ __launch_bounds__(256) void wfold_k(const float* __restrict__ EW,
                                               const float* __restrict__ W1,
                                               const float* __restrict__ EB,
                                               float* __restrict__ Weff,
                                               float* __restrict__ beff) {
  if (blockIdx.x == 16) {
    int c = threadIdx.x;
    if (c < 128) {
      float acc = 0.f;
      for (int k = 0; k < 128; k++) acc = fmaf(EB[k], W1[k * 128 + c], acc);
      beff[c] = acc;
    }
    return;
  }
  int row = blockIdx.x * 8 + (threadIdx.x >> 5);
  int c0 = (threadIdx.x & 31) * 4;
  float4 acc = make_float4(0.f, 0.f, 0.f, 0.f);
  for (int k = 0; k < 128; k++) {
    float xv = EW[row * 128 + k];
    float4 wv = *(const float4*)&W1[k * 128 + c0];
    acc.x = fmaf(xv, wv.x, acc.x);
    acc.y = fmaf(xv, wv.y, acc.y);
    acc.z = fmaf(xv, wv.z, acc.z);
    acc.w = fmaf(xv, wv.w, acc.w);
  }
  *(float4*)&Weff[row * 128 + c0] = acc;
}

// transpose + cast: W fp32 [128][128] -> Wt fp16 [col][k]
__global__ __launch_bounds__(256) void wtrans_k(const float* __restrict__ W,
                                                __half* __restrict__ Wt) {
  int idx = blockIdx.x * 256 + threadIdx.x;
  if (idx < 128 * 128) {
    int c = idx >> 7, k = idx & 127;
    Wt[idx] = __float2half(W[k * 128 + c]);
  }
}

// ---------------- CSR build (rank-based counting sort) ----------------
__global__ __launch_bounds__(256) void rank_k(const int* __restrict__ dst,
                                              int* __restrict__ cnt,
                                              int* __restrict__ rank, int ET) {
  int e = blockIdx.x * 256 + threadIdx.x;
  if (e < ET) rank[e] = atomicAdd(&cnt[dst[e]], 1);
}

__global__ __launch_bounds__(256) void block_scan_k(const int* __restrict__ cnt,
                                                    int* __restrict__ row_ptr,
                                                    int* __restrict__ bsum, int n) {
  __shared__ int s[256];
  int t = threadIdx.x;
  int idx = blockIdx.x * 256 + t;
  int val = (idx < n) ? cnt[idx] : 0;
  s[t] = val;
  __syncthreads();
  for (int off = 1; off < 256; off <<= 1) {
    int x = (t >= off) ? s[t - off] : 0;
    __syncthreads();
    s[t] += x;
    __syncthreads();
  }
  if (idx < n) row_ptr[idx] = s[t] - val;  // exclusive
  if (t == 255) bsum[blockIdx.x] = s[255];
}

__global__ __launch_bounds__(512) void bsum_scan_k(int* __restrict__ bsum, int nb) {
  __shared__ int s[512];
  int t = threadIdx.x;
  int v = (t < nb) ? bsum[t] : 0;
  s[t] = v;
  __syncthreads();
  for (int off = 1; off < 512; off <<= 1) {
    int x = (t >= off) ? s[t - off] : 0;
    __syncthreads();
    s[t] += x;
    __syncthreads();
  }
  if (t < nb) bsum[t] = s[t] - v;  // exclusive
}

__global__ __launch_bounds__(256) void add_off_k(int* __restrict__ row_ptr,
                                                 const int* __restrict__ bsum,
                                                 int n, int ET) {
  int idx = blockIdx.x * 256 + threadIdx.x;
  if (idx < n) row_ptr[idx] += bsum[idx >> 8];
  if (idx == 0) row_ptr[n] = ET;
}

__global__ __launch_bounds__(256) void fill_k(const int* __restrict__ src,
                                              const int* __restrict__ dst,
                                              const int* __restrict__ row_ptr,
                                              const int* __restrict__ rank,
                                              int* __restrict__ csr_src, int ET) {
  int e = blockIdx.x * 256 + threadIdx.x;
  if (e >= ET) return;
  csr_src[row_ptr[dst[e]] + rank[e]] = src[e];
}

// -------- fused segment softmax + aggregation: one 16-lane group per dst ------
template <int NH, bool RELU, bool HALF>
__global__ __launch_bounds__(256) void aggr_csr_k(const void* __restrict__ Hrow,
                                                  const float* __restrict__ es,
                                                  const float* __restrict__ ed,
                                                  const int* __restrict__ row_ptr,
                                                  const int* __restrict__ csr_src,
                                                  const float* __restrict__ bias,
                                                  float* __restrict__ out, int n) {
  constexpr int NC = HALF ? 128 : 64;
  constexpr int CPL = HALF ? 8 : 4;

  const int g = threadIdx.x >> 4;
  const int d = blockIdx.x * 16 + g;
  if (d >= n) return;
  const int gl = threadIdx.x & 15;
  const int ch0 = gl * CPL;
  const int head = (NH == 4) ? (ch0 >> 5) : 0;
  const int beg = row_ptr[d];
  const int deg = row_ptr[d + 1] - beg;  // >= 1 (self-loops)
  const float ed_h = ed[(size_t)d * NH + head];
  const char* __restrict__ Hb = (const char*)Hrow;

  float den = 0.f;
  float a[CPL];
#pragma unroll
  for (int c = 0; c < CPL; c++) a[c] = 0.f;

  auto loadE = [&](int idx, float& e, uint4& h) {
    bool valid = idx < deg;
    int ii = valid ? beg + idx : beg;
    int ss = csr_src[ii];
    e = valid ? es[(size_t)ss * NH + head] : -1e30f;
    h = *(const uint4*)(Hb + (size_t)ss * 256 + gl * 16);
  };
  auto consume = [&](float e, const uint4& h) {
    float vv = e + ed_h;
    vv = vv >= 0.f ? vv : 0.2f * vv;
    float ex = __expf(vv);
    den += ex;
    if constexpr (HALF) {
      const unsigned* u = &h.x;
#pragma unroll
      for (int q = 0; q < 4; q++) {
        __half2 h2 = *reinterpret_cast<const __half2*>(&u[q]);
        float2 f2 = __half22float2(h2);
        a[2 * q]     = fmaf(f2.x, ex, a[2 * q]);
        a[2 * q + 1] = fmaf(f2.y, ex, a[2 * q + 1]);
      }
    } else {
      const float4 f = *reinterpret_cast<const float4*>(&h);
      a[0] = fmaf(f.x, ex, a[0]);
      a[1] = fmaf(f.y, ex, a[1]);
      a[2] = fmaf(f.z, ex, a[2]);
      a[3] = fmaf(f.w, ex, a[3]);
    }
  };

  float eA, eB;
  uint4 hA, hB;
  loadE(0, eA, hA);
  loadE(1, eB, hB);
  for (int i = 0; i < deg; i += 2) {
    float eA2 = -1e30f, eB2 = -1e30f;
    uint4 hA2 = make_uint4(0, 0, 0, 0), hB2 = hA2;
    if (i + 2 < deg) {
      loadE(i + 2, eA2, hA2);
      loadE(i + 3, eB2, hB2);
    }
    consume(eA, hA);
    consume(eB, hB);
    eA = eA2; hA = hA2;
    eB = eB2; hB = hB2;
  }

  float inv = 1.f / den;
#pragma unroll
  for (int q = 0; q < CPL / 4; q++) {
    float4 bv = *(const float4*)&bias[ch0 + 4 * q];
    float4 o;
    o.x = fmaf(a[4 * q + 0], inv, bv.x);
    o.y = fmaf(a[4 * q + 1], inv, bv.y);
    o.z = fmaf(a[4 * q + 2], inv, bv.z);
    o.w = fmaf(a[4 * q + 3], inv, bv.w);
    if (RELU) {
      o.x = fmaxf(o.x, 0.f); o.y = fmaxf(o.y, 0.f);
      o.z = fmaxf(o.z, 0.f); o.w = fmaxf(o.w, 0.f);
    }
    *(float4*)&out[(size_t)d * NC + ch0 + 4 * q] = o;
  }
}

extern "C" void kernel_launch(void* const* d_in, const int* in_sizes, int n_in,
                              void* d_out, int out_size, void* d_ws, size_t ws_size,
                              hipStream_t stream) {
  const float* x = (const float*)d_in[0];
  const float* encw = (const float*)d_in[2];
  const float* encb = (const float*)d_in[3];
  const float* W1 = (const float*)d_in[4];
  const float* as1 = (const float*)d_in[5];
  const float* ad1 = (const float*)d_in[6];
  const float* b1 = (const float*)d_in[7];
  const float* W2 = (const float*)d_in[8];
  const float* as2 = (const float*)d_in[9];
  const float* ad2 = (const float*)d_in[10];
  const float* b2 = (const float*)d_in[11];
  const float* W3 = (const float*)d_in[12];
  const float* as3 = (const float*)d_in[13];
  const float* ad3 = (const float*)d_in[14];
  const float* b3 = (const float*)d_in[15];
  const int* ei = (const int*)d_in[16];

  const int N_ = in_sizes[0] / 128;
  const int ET = in_sizes[16] / 2;
  const int* srcp = ei;
  const int* dstp = ei + ET;
  float* out = (float*)d_out;

  // workspace carve-up (Hh aliases bufB; rank aliases bufB — dead before Hh)
  size_t NB = (size_t)N_ * 128 * sizeof(float);
  char* p = (char*)d_ws;
  float* bufA = (float*)p;      p += NB;
  float* bufB = (float*)p;      p += NB;
  __half* Hh = (__half*)bufB;   // fp16 H for layers 1/2
  int* rank = (int*)bufB;       // per-edge rank during CSR build
  float* es = (float*)p;        p += (size_t)N_ * 4 * sizeof(float);
  float* ed = (float*)p;        p += (size_t)N_ * 4 * sizeof(float);
  int* cnt = (int*)p;           p += (size_t)N_ * sizeof(int);
  int* row_ptr = (int*)p;       p += (size_t)(N_ + 1) * sizeof(int);
  int* bsum = (int*)p;          p += (size_t)((N_ + 255) / 256) * sizeof(int);
  int* csr_src = (int*)p;       p += (size_t)ET * sizeof(int);
  float* Weff = (float*)p;      p += (size_t)128 * 128 * sizeof(float);
  float* beff = (float*)p;      p += (size_t)128 * sizeof(float);
  __half* Wefft = (__half*)p;   p += (size_t)128 * 128 * sizeof(__half);
  __half* W2t = (__half*)p;     p += (size_t)128 * 128 * sizeof(__half);

  dim3 b256(256);
  int gGemm = (N_ + 31) / 32;
  int gNode = (N_ + 255) / 256;
  int gEdge = (ET + 255) / 256;
  int gAggr = (N_ + 15) / 16;
  int nb = (N_ + 255) / 256;

  // ---- weight prep + CSR build ----
  wfold_k<<<17, b256, 0, stream>>>(encw, W1, encb, Weff, beff);
  wtrans_k<<<64, b256, 0, stream>>>(Weff, Wefft);
  wtrans_k<<<64, b256, 0, stream>>>(W2, W2t);
  hipMemsetAsync(cnt, 0, (size_t)N_ * sizeof(int), stream);
  rank_k<<<gEdge, b256, 0, stream>>>(dstp, cnt, rank, ET);
  block_scan_k<<<nb, b256, 0, stream>>>(cnt, row_ptr, bsum, N_);
  bsum_scan_k<<<1, 512, 0, stream>>>(bsum, nb);
  add_off_k<<<gNode, b256, 0, stream>>>(row_ptr, bsum, N_, ET);
  fill_k<<<gEdge, b256, 0, stream>>>(srcp, dstp, row_ptr, rank, csr_src, ET);

  // ---- layer 1 (4 heads x 32): H1(fp16) = x @ Wefft + beff (MFMA) ----
  gemm_mfma_k<true><<<gGemm, b256, 0, stream>>>(x, Wefft, beff, as1, ad1,
                                                es, ed, Hh, N_);
  aggr_csr_k<4, true, true><<<gAggr, b256, 0, stream>>>(Hh, es, ed, row_ptr,
                                                        csr_src, b1, bufA, N_);

  // ---- layer 2 (4 heads x 32): H2(fp16) = bufA @ W2t (MFMA) ----
  gemm_mfma_k<false><<<gGemm, b256, 0, stream>>>(bufA, W2t, nullptr, as2, ad2,
                                                 es, ed, Hh, N_);
  aggr_csr_k<4, true, true><<<gAggr, b256, 0, stream>>>(Hh, es, ed, row_ptr,
                                                        csr_src, b2, bufA, N_);

  // ---- layer 3 (1 head x 64): fp32 VALU (feeds output directly) ----
  gemm_k<64, false, 1><<<gGemm, b256, 0, stream>>>(bufA, W3, nullptr, as3, ad3,
                                                   es, ed, bufB, N_);
  aggr_csr_k<1, false, false><<<gAggr, b256, 0, stream>>>(bufB, es, ed, row_ptr,
                                                          csr_src, b3, out, N_);
}